// Round 1
// baseline (779.630 us; speedup 1.0000x reference)
//
#include <hip/hip_runtime.h>
#include <stdint.h>

// ---------- bf16 helpers ----------
__device__ inline float bf2f(uint16_t u) {
    uint32_t x = ((uint32_t)u) << 16;
    float f;
    __builtin_memcpy(&f, &x, 4);
    return f;
}
__device__ inline uint16_t f2bf(float f) {
    uint32_t x;
    __builtin_memcpy(&x, &f, 4);
    uint32_t r = (x + 0x7FFFu + ((x >> 16) & 1u)) >> 16;
    return (uint16_t)r;
}

// ---------------------------------------------------------------------------
// Kernel A: handcrafted features. One block per (channel, image).
// LDS-stages the 128x128 channel (floored*255), computes sum/sumsq during the
// global load, then Sobel (reflect-101) magnitude mean from LDS.
// f layout: f[b*16 + 0..2]=edge, [3..5]=brightness, [6..8]=contrast
// ---------------------------------------------------------------------------
__global__ __launch_bounds__(256) void k_handcrafted(const float* __restrict__ img,
                                                     float* __restrict__ f) {
    __shared__ float p[128 * 128];  // 64 KB; first 12 floats reused for reduction
    int c = blockIdx.x, b = blockIdx.y;
    const float* src = img + (((size_t)(b * 3 + c)) << 14);
    int tid = threadIdx.x;
    float sum = 0.f, sumsq = 0.f;
    for (int it = 0; it < 64; ++it) {
        int idx = tid + (it << 8);
        float v = floorf(src[idx] * 255.0f);
        p[idx] = v;
        sum += v;
        sumsq += v * v;
    }
    __syncthreads();
    float esum = 0.f;
    for (int it = 0; it < 64; ++it) {
        int idx = tid + (it << 8);
        int r = idx >> 7, cc = idx & 127;
        int rm = (r == 0) ? 1 : (r - 1), rp = (r == 127) ? 126 : (r + 1);
        int cm = (cc == 0) ? 1 : (cc - 1), cp = (cc == 127) ? 126 : (cc + 1);
        float a0 = p[(rm << 7) + cm], a1 = p[(rm << 7) + cc], a2 = p[(rm << 7) + cp];
        float b0 = p[(r << 7) + cm], b2 = p[(r << 7) + cp];
        float c0 = p[(rp << 7) + cm], c1 = p[(rp << 7) + cc], c2 = p[(rp << 7) + cp];
        float gx = (a2 - a0) + 2.f * (b2 - b0) + (c2 - c0);
        float gy = (c0 + 2.f * c1 + c2) - (a0 + 2.f * a1 + a2);
        esum += sqrtf(gx * gx + gy * gy);
    }
    // reduce the three partials across the block
    for (int off = 32; off; off >>= 1) {
        sum += __shfl_down(sum, off);
        sumsq += __shfl_down(sumsq, off);
        esum += __shfl_down(esum, off);
    }
    __syncthreads();  // everyone done reading p -> safe to reuse
    int w = tid >> 6;
    if ((tid & 63) == 0) {
        p[w * 3 + 0] = sum;
        p[w * 3 + 1] = sumsq;
        p[w * 3 + 2] = esum;
    }
    __syncthreads();
    if (tid == 0) {
        float S = 0.f, Q = 0.f, E = 0.f;
        for (int i = 0; i < 4; ++i) {
            S += p[i * 3 + 0];
            Q += p[i * 3 + 1];
            E += p[i * 3 + 2];
        }
        const float inv = 1.0f / 16384.0f;
        float mean = S * inv;
        float var = Q * inv - mean * mean;
        float cont = sqrtf(fmaxf(var, 0.f));
        float edge = E * inv;
        f[b * 16 + c] = edge;
        f[b * 16 + 3 + c] = mean;
        f[b * 16 + 6 + c] = cont;
    }
}

// ---------------------------------------------------------------------------
// Kernel B: conv1(3->32, 3x3, pad1) + ReLU + maxpool2 -> pooled1 [B,32,64,64] bf16
// Block: 256 threads, one 16x16 pooled tile (=32x32 conv outputs) per block.
// Grid: (16 tiles, B images)
// ---------------------------------------------------------------------------
__global__ __launch_bounds__(256) void k_conv1(const float* __restrict__ img,
                                               const float* __restrict__ W1,
                                               const float* __restrict__ b1,
                                               uint16_t* __restrict__ pooled1) {
    __shared__ float s_in[3 * 34 * 34];  // 13872 B
    __shared__ float s_w[32 * 27];
    __shared__ float s_b[32];
    int tile = blockIdx.x;
    int b = blockIdx.y;
    int ty = tile >> 2, tx = tile & 3;
    int tid = threadIdx.x;
    int Y0 = ty * 32, X0 = tx * 32;  // conv-output origin (input origin is -1)
    for (int j = tid; j < 3 * 34 * 34; j += 256) {
        int ic = j / 1156;
        int rem = j - ic * 1156;
        int r = rem / 34, cc2 = rem - r * 34;
        int gy = Y0 - 1 + r, gx = X0 - 1 + cc2;
        float v = 0.f;
        if ((unsigned)gy < 128u && (unsigned)gx < 128u)
            v = img[(((size_t)b * 3 + ic) << 14) + (gy << 7) + gx];
        s_in[j] = v;
    }
    for (int j = tid; j < 864; j += 256) s_w[j] = W1[j];
    if (tid < 32) s_b[tid] = b1[tid];
    __syncthreads();

    int py = tid >> 4, px = tid & 15;
    float win[3][4][4];
#pragma unroll
    for (int ic = 0; ic < 3; ++ic)
#pragma unroll
        for (int r = 0; r < 4; ++r)
#pragma unroll
            for (int c2 = 0; c2 < 4; ++c2)
                win[ic][r][c2] = s_in[ic * 1156 + (2 * py + r) * 34 + 2 * px + c2];

    int Yp = ty * 16 + py, Xp = tx * 16 + px;
    for (int oc = 0; oc < 32; ++oc) {
        float bb = s_b[oc];
        float a00 = bb, a01 = bb, a10 = bb, a11 = bb;
#pragma unroll
        for (int ic = 0; ic < 3; ++ic)
#pragma unroll
            for (int dy = 0; dy < 3; ++dy)
#pragma unroll
                for (int dx = 0; dx < 3; ++dx) {
                    float w = s_w[((oc * 3 + ic) * 3 + dy) * 3 + dx];
                    a00 += w * win[ic][dy][dx];
                    a01 += w * win[ic][dy][dx + 1];
                    a10 += w * win[ic][dy + 1][dx];
                    a11 += w * win[ic][dy + 1][dx + 1];
                }
        float m = fmaxf(fmaxf(a00, a01), fmaxf(a10, a11));
        m = fmaxf(m, 0.f);
        pooled1[(((size_t)b * 32 + oc) << 12) + (Yp << 6) + Xp] = f2bf(m);
    }
}

// ---------------------------------------------------------------------------
// Kernel C: conv2(32->64, 3x3, pad1) + ReLU + maxpool2 -> pooled2 [B,64,32,32] bf16
// Block: 256 threads = 4 waves; each wave owns 16 output channels; each thread
// one 8x8-tile pooled position with 16-oc x 4-conv-pos accumulators.
// Grid: (16 tiles, B images)
// ---------------------------------------------------------------------------
__global__ __launch_bounds__(256) void k_conv2(const uint16_t* __restrict__ pooled1,
                                               const float* __restrict__ W2,
                                               const float* __restrict__ b2v,
                                               uint16_t* __restrict__ pooled2) {
    __shared__ uint16_t s_in[32 * 18 * 18];  // 20736 B
    int tile = blockIdx.x;
    int b = blockIdx.y;
    int ty = tile >> 2, tx = tile & 3;
    int tid = threadIdx.x;
    int Y0 = ty * 16, X0 = tx * 16;  // conv-output origin in 64x64 conv space
    for (int j = tid; j < 32 * 324; j += 256) {
        int ic = j / 324;
        int rem = j - ic * 324;
        int r = rem / 18, cc2 = rem - r * 18;
        int gy = Y0 - 1 + r, gx = X0 - 1 + cc2;
        uint16_t v = 0;
        if ((unsigned)gy < 64u && (unsigned)gx < 64u)
            v = pooled1[(((size_t)b * 32 + ic) << 12) + (gy << 6) + gx];
        s_in[j] = v;
    }
    __syncthreads();

    int pos = tid & 63, wv = tid >> 6;
    int py = pos >> 3, px = pos & 7;
    int oc0 = __builtin_amdgcn_readfirstlane(wv) * 16;  // wave-uniform -> scalar weight loads
    float acc[16][4];
#pragma unroll
    for (int k = 0; k < 16; ++k) {
        float bb = b2v[oc0 + k];
        acc[k][0] = bb;
        acc[k][1] = bb;
        acc[k][2] = bb;
        acc[k][3] = bb;
    }
    for (int ic = 0; ic < 32; ++ic) {
        float in[4][4];
#pragma unroll
        for (int r = 0; r < 4; ++r)
#pragma unroll
            for (int cp = 0; cp < 2; ++cp) {
                uint32_t v = *(const uint32_t*)&s_in[ic * 324 + (2 * py + r) * 18 + 2 * px + 2 * cp];
                in[r][2 * cp] = bf2f((uint16_t)(v & 0xffffu));
                in[r][2 * cp + 1] = bf2f((uint16_t)(v >> 16));
            }
        const float* wp = W2 + ((size_t)oc0 * 32 + ic) * 9;
#pragma unroll
        for (int k = 0; k < 16; ++k) {
            const float* w = wp + (size_t)k * 288;
#pragma unroll
            for (int dy = 0; dy < 3; ++dy)
#pragma unroll
                for (int dx = 0; dx < 3; ++dx) {
                    float wv2 = w[dy * 3 + dx];
                    acc[k][0] += wv2 * in[dy][dx];
                    acc[k][1] += wv2 * in[dy][dx + 1];
                    acc[k][2] += wv2 * in[dy + 1][dx];
                    acc[k][3] += wv2 * in[dy + 1][dx + 1];
                }
        }
    }
    int Yp = ty * 8 + py, Xp = tx * 8 + px;
#pragma unroll
    for (int k = 0; k < 16; ++k) {
        float m = fmaxf(fmaxf(acc[k][0], acc[k][1]), fmaxf(acc[k][2], acc[k][3]));
        m = fmaxf(m, 0.f);
        pooled2[(((size_t)b * 64 + oc0 + k) << 10) + (Yp << 5) + Xp] = f2bf(m);
    }
}

// ---------------------------------------------------------------------------
// Kernel D1: attention conv (64->1, 7x7, pad3) + sigmoid -> attn [B,32,32] fp32
// Block per image; 8-channel LDS chunks; each thread computes a 2x2 output block.
// ---------------------------------------------------------------------------
__global__ __launch_bounds__(256) void k_attn(const uint16_t* __restrict__ pooled2,
                                              const float* __restrict__ Wa,
                                              const float* __restrict__ ba,
                                              float* __restrict__ attn) {
    __shared__ uint16_t s_in[8 * 38 * 38];  // 23104 B
    int b = blockIdx.x;
    int tid = threadIdx.x;
    int y0 = (tid >> 4) * 2, x0 = (tid & 15) * 2;
    float a0 = ba[0];
    float acc[4] = {a0, a0, a0, a0};
    for (int cc = 0; cc < 8; ++cc) {
        __syncthreads();
        for (int j = tid; j < 8 * 1444; j += 256) {
            int ch = j / 1444;
            int rem = j - ch * 1444;
            int r = rem / 38, c2 = rem - r * 38;
            int gy = r - 3, gx = c2 - 3;
            uint16_t v = 0;
            if ((unsigned)gy < 32u && (unsigned)gx < 32u)
                v = pooled2[(((size_t)b * 64 + cc * 8 + ch) << 10) + (gy << 5) + gx];
            s_in[j] = v;
        }
        __syncthreads();
        for (int ch = 0; ch < 8; ++ch) {
            float win[8][8];
#pragma unroll
            for (int r = 0; r < 8; ++r)
#pragma unroll
                for (int cp = 0; cp < 4; ++cp) {
                    uint32_t v = *(const uint32_t*)&s_in[ch * 1444 + (y0 + r) * 38 + x0 + 2 * cp];
                    win[r][2 * cp] = bf2f((uint16_t)(v & 0xffffu));
                    win[r][2 * cp + 1] = bf2f((uint16_t)(v >> 16));
                }
            const float* w = Wa + (cc * 8 + ch) * 49;
#pragma unroll
            for (int a = 0; a < 2; ++a)
#pragma unroll
                for (int bb = 0; bb < 2; ++bb) {
                    float s = 0.f;
#pragma unroll
                    for (int dy = 0; dy < 7; ++dy)
#pragma unroll
                        for (int dx = 0; dx < 7; ++dx)
                            s += w[dy * 7 + dx] * win[a + dy][bb + dx];
                    acc[a * 2 + bb] += s;
                }
        }
    }
#pragma unroll
    for (int a = 0; a < 2; ++a)
#pragma unroll
        for (int bb = 0; bb < 2; ++bb) {
            float v = acc[a * 2 + bb];
            attn[((size_t)b << 10) + ((size_t)(y0 + a) << 5) + (x0 + bb)] =
                1.f / (1.f + __expf(-v));
        }
}

// ---------------------------------------------------------------------------
// Kernel D2: FC partials. C[b,o] = sum_k (pooled2*attn)[b,k] * Wfc[o,k]
// Split-K: grid (32 image-groups of 8, 16 k-chunks of 4096). x-hat staged in
// 64KB LDS (bf16) so each Wfc element is loaded once per 8 images.
// partial layout: [kc][b][64] fp32
// ---------------------------------------------------------------------------
__global__ __launch_bounds__(256) void k_fc(const uint16_t* __restrict__ pooled2,
                                            const float* __restrict__ attn,
                                            const float* __restrict__ Wfc,
                                            float* __restrict__ partial) {
    __shared__ uint16_t xh[8 * 4096];  // 64 KB
    int gimg = blockIdx.x;  // 0..31
    int kc = blockIdx.y;    // 0..15
    int b0 = gimg * 8;
    int K0 = kc * 4096;
    int tid = threadIdx.x;
    for (int j = tid; j < 8 * 4096; j += 256) {
        int im = j >> 12;
        int k = j & 4095;
        int gk = K0 + k;
        int s = gk & 1023;
        int bimg = b0 + im;
        float v = bf2f(pooled2[(((size_t)bimg) << 16) + gk]) * attn[((size_t)bimg << 10) + s];
        xh[j] = f2bf(v);
    }
    __syncthreads();

    int wv = tid >> 6, l = tid & 63;
    float acc[13][8];
#pragma unroll
    for (int j = 0; j < 13; ++j)
#pragma unroll
        for (int im = 0; im < 8; ++im) acc[j][im] = 0.f;

#pragma unroll 2
    for (int i = 0; i < 64; ++i) {
        int k = (i << 6) + l;
        float xv[8];
#pragma unroll
        for (int im = 0; im < 8; ++im) xv[im] = bf2f(xh[(im << 12) + k]);
#pragma unroll
        for (int j = 0; j < 13; ++j) {
            int o = wv + (j << 2);
            if (o < 50) {
                float w = Wfc[(size_t)o * 65536 + K0 + k];
#pragma unroll
                for (int im = 0; im < 8; ++im) acc[j][im] += w * xv[im];
            }
        }
    }
#pragma unroll
    for (int j = 0; j < 13; ++j) {
        int o = wv + (j << 2);
#pragma unroll
        for (int im = 0; im < 8; ++im) {
            float v = acc[j][im];
            for (int off = 32; off; off >>= 1) v += __shfl_xor(v, off);
            if (l == im && o < 50)
                partial[(((size_t)kc * 256 + (b0 + im)) << 6) + o] = v;
        }
    }
}

// ---------------------------------------------------------------------------
// Kernel E: MLP head + fusion. One wave per image.
// ---------------------------------------------------------------------------
__global__ __launch_bounds__(64) void k_head(const float* __restrict__ fbuf,
                                             const float* __restrict__ partial,
                                             const float* __restrict__ Wh1, const float* __restrict__ bh1,
                                             const float* __restrict__ Wh2, const float* __restrict__ bh2,
                                             const float* __restrict__ Wh3, const float* __restrict__ bh3,
                                             const float* __restrict__ bfc,
                                             const float* __restrict__ Wf, const float* __restrict__ bf_,
                                             const float* __restrict__ Wc, const float* __restrict__ bc,
                                             float* __restrict__ out) {
    __shared__ float fl[9];
    __shared__ float h1[32];
    __shared__ float h2[64];
    __shared__ float cat[100];
    int b = blockIdx.x;
    int l = threadIdx.x;
    if (l < 9) fl[l] = fbuf[b * 16 + l];
    __syncthreads();
    if (l < 32) {
        float a = bh1[l];
        for (int i = 0; i < 9; ++i) a += fl[i] * Wh1[l * 9 + i];
        h1[l] = fmaxf(a, 0.f);
    }
    __syncthreads();
    {
        float a = bh2[l];
        for (int i = 0; i < 32; ++i) a += h1[i] * Wh2[l * 32 + i];
        h2[l] = fmaxf(a, 0.f);
    }
    __syncthreads();
    if (l < 50) {
        float a = bh3[l];
        for (int i = 0; i < 64; ++i) a += h2[i] * Wh3[l * 64 + i];
        cat[50 + l] = fmaxf(a, 0.f);
        float s = bfc[l];
        for (int kc2 = 0; kc2 < 16; ++kc2) s += partial[(((size_t)kc2 * 256 + b) << 6) + l];
        cat[l] = fmaxf(s, 0.f);
    }
    __syncthreads();
    float a = bf_[l];
    for (int i = 0; i < 100; ++i) a += cat[i] * Wf[l * 100 + i];
    a = fmaxf(a, 0.f);
    float v = a * Wc[l];
    for (int off = 32; off; off >>= 1) v += __shfl_down(v, off);
    if (l == 0) out[b] = 1.f / (1.f + __expf(-(v + bc[0])));
}

// ---------------------------------------------------------------------------
extern "C" void kernel_launch(void* const* d_in, const int* in_sizes, int n_in,
                              void* d_out, int out_size, void* d_ws, size_t ws_size,
                              hipStream_t stream) {
    const float* images = (const float*)d_in[0];
    const float* W1 = (const float*)d_in[1];
    const float* b1 = (const float*)d_in[2];
    const float* W2 = (const float*)d_in[3];
    const float* b2 = (const float*)d_in[4];
    const float* Wa = (const float*)d_in[5];
    const float* ba = (const float*)d_in[6];
    const float* Wfc = (const float*)d_in[7];
    const float* bfc = (const float*)d_in[8];
    const float* Wh1 = (const float*)d_in[9];
    const float* bh1 = (const float*)d_in[10];
    const float* Wh2 = (const float*)d_in[11];
    const float* bh2 = (const float*)d_in[12];
    const float* Wh3 = (const float*)d_in[13];
    const float* bh3 = (const float*)d_in[14];
    const float* Wf = (const float*)d_in[15];
    const float* bf_ = (const float*)d_in[16];
    const float* Wc = (const float*)d_in[17];
    const float* bc = (const float*)d_in[18];

    // workspace layout (bytes)
    //   pooled1 bf16 [256,32,64,64]  : 67108864
    //   pooled2 bf16 [256,64,32,32]  : 33554432   @ 67108864
    //   attn    f32  [256,32,32]     : 1048576    @ 100663296
    //   fbuf    f32  [256,16]        : 16384      @ 101711872
    //   partial f32  [16,256,64]     : 1048576    @ 101728256
    const size_t NEEDED = 102776832;
    if (ws_size < NEEDED) return;  // loud deterministic failure rather than corruption

    char* ws = (char*)d_ws;
    uint16_t* pooled1 = (uint16_t*)ws;
    uint16_t* pooled2 = (uint16_t*)(ws + 67108864);
    float* attn = (float*)(ws + 100663296);
    float* fbuf = (float*)(ws + 101711872);
    float* partial = (float*)(ws + 101728256);
    float* out = (float*)d_out;

    hipLaunchKernelGGL(k_handcrafted, dim3(3, 256), dim3(256), 0, stream, images, fbuf);
    hipLaunchKernelGGL(k_conv1, dim3(16, 256), dim3(256), 0, stream, images, W1, b1, pooled1);
    hipLaunchKernelGGL(k_conv2, dim3(16, 256), dim3(256), 0, stream, pooled1, W2, b2, pooled2);
    hipLaunchKernelGGL(k_attn, dim3(256), dim3(256), 0, stream, pooled2, Wa, ba, attn);
    hipLaunchKernelGGL(k_fc, dim3(32, 16), dim3(256), 0, stream, pooled2, attn, Wfc, partial);
    hipLaunchKernelGGL(k_head, dim3(256), dim3(64), 0, stream, fbuf, partial,
                       Wh1, bh1, Wh2, bh2, Wh3, bh3, bfc, Wf, bf_, Wc, bc, out);
}

// Round 2
// 514.815 us; speedup vs baseline: 1.5144x; 1.5144x over previous
//
#include <hip/hip_runtime.h>
#include <stdint.h>

typedef __bf16 bf16x8 __attribute__((ext_vector_type(8)));
typedef float f32x4 __attribute__((ext_vector_type(4)));

// ---------- bf16 helpers ----------
__device__ inline float bf2f(uint16_t u) {
    uint32_t x = ((uint32_t)u) << 16;
    float f;
    __builtin_memcpy(&f, &x, 4);
    return f;
}
__device__ inline uint16_t f2bf(float f) {
    uint32_t x;
    __builtin_memcpy(&x, &f, 4);
    uint32_t r = (x + 0x7FFFu + ((x >> 16) & 1u)) >> 16;
    return (uint16_t)r;
}

// ---------------------------------------------------------------------------
// Weight prep: W2 [64][32][3][3] f32 -> wA [tap=9][oc=64][ic=32] bf16
// ---------------------------------------------------------------------------
__global__ __launch_bounds__(256) void k_prep_w2(const float* __restrict__ W2,
                                                 uint16_t* __restrict__ wA) {
    int j = blockIdx.x * 256 + threadIdx.x;
    if (j >= 18432) return;
    int t = j >> 11, rem = j & 2047, oc = rem >> 5, ic = rem & 31;
    int dy = t / 3, dx = t - dy * 3;
    wA[j] = f2bf(W2[(oc * 32 + ic) * 9 + dy * 3 + dx]);
}

// Wfc f32 -> bf16 (3,276,800 elems, 4 per thread)
__global__ __launch_bounds__(256) void k_prep_wfc(const float* __restrict__ Wfc,
                                                  uint16_t* __restrict__ wfcb) {
    int j = blockIdx.x * 256 + threadIdx.x;
    float4 v = ((const float4*)Wfc)[j];
    ushort4 o;
    o.x = f2bf(v.x);
    o.y = f2bf(v.y);
    o.z = f2bf(v.z);
    o.w = f2bf(v.w);
    ((ushort4*)wfcb)[j] = o;
}

// ---------------------------------------------------------------------------
// Kernel A: handcrafted features. One block per (channel, image).
// ---------------------------------------------------------------------------
__global__ __launch_bounds__(256) void k_handcrafted(const float* __restrict__ img,
                                                     float* __restrict__ f) {
    __shared__ float p[128 * 128];
    int c = blockIdx.x, b = blockIdx.y;
    const float* src = img + (((size_t)(b * 3 + c)) << 14);
    int tid = threadIdx.x;
    float sum = 0.f, sumsq = 0.f;
    for (int it = 0; it < 64; ++it) {
        int idx = tid + (it << 8);
        float v = floorf(src[idx] * 255.0f);
        p[idx] = v;
        sum += v;
        sumsq += v * v;
    }
    __syncthreads();
    float esum = 0.f;
    for (int it = 0; it < 64; ++it) {
        int idx = tid + (it << 8);
        int r = idx >> 7, cc = idx & 127;
        int rm = (r == 0) ? 1 : (r - 1), rp = (r == 127) ? 126 : (r + 1);
        int cm = (cc == 0) ? 1 : (cc - 1), cp = (cc == 127) ? 126 : (cc + 1);
        float a0 = p[(rm << 7) + cm], a1 = p[(rm << 7) + cc], a2 = p[(rm << 7) + cp];
        float b0 = p[(r << 7) + cm], b2 = p[(r << 7) + cp];
        float c0 = p[(rp << 7) + cm], c1 = p[(rp << 7) + cc], c2 = p[(rp << 7) + cp];
        float gx = (a2 - a0) + 2.f * (b2 - b0) + (c2 - c0);
        float gy = (c0 + 2.f * c1 + c2) - (a0 + 2.f * a1 + a2);
        esum += sqrtf(gx * gx + gy * gy);
    }
    for (int off = 32; off; off >>= 1) {
        sum += __shfl_down(sum, off);
        sumsq += __shfl_down(sumsq, off);
        esum += __shfl_down(esum, off);
    }
    __syncthreads();
    int w = tid >> 6;
    if ((tid & 63) == 0) {
        p[w * 3 + 0] = sum;
        p[w * 3 + 1] = sumsq;
        p[w * 3 + 2] = esum;
    }
    __syncthreads();
    if (tid == 0) {
        float S = 0.f, Q = 0.f, E = 0.f;
        for (int i = 0; i < 4; ++i) {
            S += p[i * 3 + 0];
            Q += p[i * 3 + 1];
            E += p[i * 3 + 2];
        }
        const float inv = 1.0f / 16384.0f;
        float mean = S * inv;
        float var = Q * inv - mean * mean;
        f[b * 16 + c] = E * inv;
        f[b * 16 + 3 + c] = mean;
        f[b * 16 + 6 + c] = sqrtf(fmaxf(var, 0.f));
    }
}

// ---------------------------------------------------------------------------
// Kernel B: conv1(3->32,3x3,pad1)+ReLU+maxpool2 -> pooled1 NHWC [B,64,64,32] bf16
// ---------------------------------------------------------------------------
__global__ __launch_bounds__(256) void k_conv1(const float* __restrict__ img,
                                               const float* __restrict__ W1,
                                               const float* __restrict__ b1,
                                               uint16_t* __restrict__ pooled1) {
    __shared__ float s_in[3 * 34 * 34];
    __shared__ float s_w[32 * 27];
    __shared__ float s_b[32];
    int tile = blockIdx.x;
    int b = blockIdx.y;
    int ty = tile >> 2, tx = tile & 3;
    int tid = threadIdx.x;
    int Y0 = ty * 32, X0 = tx * 32;
    for (int j = tid; j < 3 * 34 * 34; j += 256) {
        int ic = j / 1156;
        int rem = j - ic * 1156;
        int r = rem / 34, cc2 = rem - r * 34;
        int gy = Y0 - 1 + r, gx = X0 - 1 + cc2;
        float v = 0.f;
        if ((unsigned)gy < 128u && (unsigned)gx < 128u)
            v = img[(((size_t)b * 3 + ic) << 14) + (gy << 7) + gx];
        s_in[j] = v;
    }
    for (int j = tid; j < 864; j += 256) s_w[j] = W1[j];
    if (tid < 32) s_b[tid] = b1[tid];
    __syncthreads();

    int py = tid >> 4, px = tid & 15;
    float win[3][4][4];
#pragma unroll
    for (int ic = 0; ic < 3; ++ic)
#pragma unroll
        for (int r = 0; r < 4; ++r)
#pragma unroll
            for (int c2 = 0; c2 < 4; ++c2)
                win[ic][r][c2] = s_in[ic * 1156 + (2 * py + r) * 34 + 2 * px + c2];

    uint32_t packed[16];
#pragma unroll
    for (int op = 0; op < 16; ++op) {
        uint32_t pk = 0;
#pragma unroll
        for (int half = 0; half < 2; ++half) {
            int oc = 2 * op + half;
            float bb = s_b[oc];
            float a00 = bb, a01 = bb, a10 = bb, a11 = bb;
#pragma unroll
            for (int ic = 0; ic < 3; ++ic)
#pragma unroll
                for (int dy = 0; dy < 3; ++dy)
#pragma unroll
                    for (int dx = 0; dx < 3; ++dx) {
                        float w = s_w[((oc * 3 + ic) * 3 + dy) * 3 + dx];
                        a00 += w * win[ic][dy][dx];
                        a01 += w * win[ic][dy][dx + 1];
                        a10 += w * win[ic][dy + 1][dx];
                        a11 += w * win[ic][dy + 1][dx + 1];
                    }
            float m = fmaxf(fmaxf(a00, a01), fmaxf(a10, a11));
            m = fmaxf(m, 0.f);
            pk |= ((uint32_t)f2bf(m)) << (16 * half);
        }
        packed[op] = pk;
    }
    int Yp = ty * 16 + py, Xp = tx * 16 + px;
    uint4* dst = (uint4*)pooled1 + ((((size_t)b << 12) + (Yp << 6) + Xp) << 2);
#pragma unroll
    for (int q = 0; q < 4; ++q)
        dst[q] = make_uint4(packed[4 * q], packed[4 * q + 1], packed[4 * q + 2], packed[4 * q + 3]);
}

// ---------------------------------------------------------------------------
// Kernel C: conv2 via MFMA implicit GEMM (tap-decomposed, K=32 per tap).
// pooled1 NHWC bf16 in, pooled2 NCHW bf16 out.
// Block: 256 thr = 4 waves; tile = 8 conv rows x 32 conv cols, all 64 oc.
// wave: oc-half = w&1, x-tile(16) = w>>1; per yp: 12 ds_read_b128 B-frags,
// 36 mfma_16x16x32_bf16. Grid (16, 256).
// ---------------------------------------------------------------------------
__global__ __launch_bounds__(256) void k_conv2_mfma(const uint16_t* __restrict__ pooled1,
                                                    const uint16_t* __restrict__ wA,
                                                    const float* __restrict__ b2v,
                                                    uint16_t* __restrict__ pooled2) {
    __shared__ uint16_t s_in[10 * 34 * 32];   // 21760 B, row0 = conv row -1
    __shared__ uint16_t s_out[64 * 4 * 16];   // 8192 B
    const int bx = blockIdx.x;                // 0..15
    const int b = blockIdx.y;
    const int tx = bx >> 3, ty = bx & 7;
    const int X0 = tx * 32, Y0 = ty * 8;
    const int tid = threadIdx.x;

    // stage 10 rows x 34 px x 32 ic (16B chunks), zero outside image
    for (int j = tid; j < 1360; j += 256) {
        int r = j / 136;
        int rem = j - r * 136;
        int px = rem >> 2, c4 = rem & 3;
        int gy = Y0 - 1 + r, gx = X0 - 1 + px;
        uint4 v = make_uint4(0, 0, 0, 0);
        if ((unsigned)gy < 64u && (unsigned)gx < 64u)
            v = ((const uint4*)pooled1)[((((size_t)b << 12) + gy * 64 + gx) << 2) + c4];
        *(uint4*)&s_in[(r * 34 + px) * 32 + c4 * 8] = v;
    }

    const int wv = tid >> 6, lane = tid & 63;
    const int ocq = wv & 1, xth = wv >> 1;
    const int rowl = lane & 15, kg = lane >> 4;

    // A fragments: lane holds wA[t][ocq*32+g*16+rowl][kg*8 .. +7]
    bf16x8 afr[9][2];
#pragma unroll
    for (int t = 0; t < 9; ++t)
#pragma unroll
        for (int g = 0; g < 2; ++g)
            afr[t][g] = *(const bf16x8*)(wA + t * 2048 + (ocq * 32 + g * 16 + rowl) * 32 + kg * 8);
    float bias[2][4];
#pragma unroll
    for (int g = 0; g < 2; ++g)
#pragma unroll
        for (int r = 0; r < 4; ++r)
            bias[g][r] = b2v[ocq * 32 + g * 16 + kg * 4 + r];

    __syncthreads();

    for (int yp = 0; yp < 4; ++yp) {
        f32x4 acc[2][2];
#pragma unroll
        for (int p = 0; p < 2; ++p)
#pragma unroll
            for (int g = 0; g < 2; ++g)
#pragma unroll
                for (int r = 0; r < 4; ++r) acc[p][g][r] = bias[g][r];

        // B frags: input rows 2yp+0..3 (local), cols xth*16 + rowl + dx
        bf16x8 bfr[4][3];
#pragma unroll
        for (int rr = 0; rr < 4; ++rr)
#pragma unroll
            for (int dx = 0; dx < 3; ++dx) {
                int pix = (2 * yp + rr) * 34 + xth * 16 + rowl + dx;
                bfr[rr][dx] = *(const bf16x8*)(s_in + pix * 32 + kg * 8);
            }
#pragma unroll
        for (int dy = 0; dy < 3; ++dy)
#pragma unroll
            for (int dx = 0; dx < 3; ++dx) {
                int t = dy * 3 + dx;
#pragma unroll
                for (int g = 0; g < 2; ++g) {
                    acc[0][g] = __builtin_amdgcn_mfma_f32_16x16x32_bf16(afr[t][g], bfr[dy][dx], acc[0][g], 0, 0, 0);
                    acc[1][g] = __builtin_amdgcn_mfma_f32_16x16x32_bf16(afr[t][g], bfr[dy + 1][dx], acc[1][g], 0, 0, 0);
                }
            }
        // 2x2 maxpool + relu; C/D: col(=conv x)=lane&15, row(=oc)= kg*4+reg
#pragma unroll
        for (int g = 0; g < 2; ++g)
#pragma unroll
            for (int r = 0; r < 4; ++r) {
                float m = fmaxf(acc[0][g][r], acc[1][g][r]);
                m = fmaxf(m, 0.f);
                float o = fmaxf(m, __shfl_xor(m, 1));
                if (!(lane & 1)) {
                    int oc = ocq * 32 + g * 16 + kg * 4 + r;
                    int px = xth * 8 + (rowl >> 1);
                    s_out[(oc * 4 + yp) * 16 + px] = f2bf(o);
                }
            }
    }
    __syncthreads();
    // coalesced NCHW store: this block covers pooled rows ty*4..+3, cols tx*16..+15
    const int PY0 = ty * 4, PX0 = tx * 16;
    for (int j = tid; j < 512; j += 256) {
        int oc = j >> 3, py = (j >> 1) & 3, h = j & 1;
        uint4 v = *(const uint4*)&s_out[(oc * 4 + py) * 16 + h * 8];
        *(uint4*)&pooled2[(((size_t)b * 64 + oc) << 10) + (PY0 + py) * 32 + PX0 + h * 8] = v;
    }
}

// ---------------------------------------------------------------------------
// Kernel D1: attention conv (64->1, 7x7, pad3) + sigmoid -> attn [B,32,32] fp32
// ---------------------------------------------------------------------------
__global__ __launch_bounds__(256) void k_attn(const uint16_t* __restrict__ pooled2,
                                              const float* __restrict__ Wa,
                                              const float* __restrict__ ba,
                                              float* __restrict__ attn) {
    __shared__ uint16_t s_in[8 * 38 * 38];
    int b = blockIdx.x;
    int tid = threadIdx.x;
    int y0 = (tid >> 4) * 2, x0 = (tid & 15) * 2;
    float a0 = ba[0];
    float acc[4] = {a0, a0, a0, a0};
    for (int cc = 0; cc < 8; ++cc) {
        __syncthreads();
        for (int j = tid; j < 8 * 1444; j += 256) {
            int ch = j / 1444;
            int rem = j - ch * 1444;
            int r = rem / 38, c2 = rem - r * 38;
            int gy = r - 3, gx = c2 - 3;
            uint16_t v = 0;
            if ((unsigned)gy < 32u && (unsigned)gx < 32u)
                v = pooled2[(((size_t)b * 64 + cc * 8 + ch) << 10) + (gy << 5) + gx];
            s_in[j] = v;
        }
        __syncthreads();
        for (int ch = 0; ch < 8; ++ch) {
            float win[8][8];
#pragma unroll
            for (int r = 0; r < 8; ++r)
#pragma unroll
                for (int cp = 0; cp < 4; ++cp) {
                    uint32_t v = *(const uint32_t*)&s_in[ch * 1444 + (y0 + r) * 38 + x0 + 2 * cp];
                    win[r][2 * cp] = bf2f((uint16_t)(v & 0xffffu));
                    win[r][2 * cp + 1] = bf2f((uint16_t)(v >> 16));
                }
            const float* w = Wa + (cc * 8 + ch) * 49;
#pragma unroll
            for (int a = 0; a < 2; ++a)
#pragma unroll
                for (int bb = 0; bb < 2; ++bb) {
                    float s = 0.f;
#pragma unroll
                    for (int dy = 0; dy < 7; ++dy)
#pragma unroll
                        for (int dx = 0; dx < 7; ++dx)
                            s += w[dy * 7 + dx] * win[a + dy][bb + dx];
                    acc[a * 2 + bb] += s;
                }
        }
    }
#pragma unroll
    for (int a = 0; a < 2; ++a)
#pragma unroll
        for (int bb = 0; bb < 2; ++bb) {
            float v = acc[a * 2 + bb];
            attn[((size_t)b << 10) + ((size_t)(y0 + a) << 5) + (x0 + bb)] =
                1.f / (1.f + __expf(-v));
        }
}

// ---------------------------------------------------------------------------
// Kernel D2: FC partials with bf16 weights.
// ---------------------------------------------------------------------------
__global__ __launch_bounds__(256) void k_fc(const uint16_t* __restrict__ pooled2,
                                            const float* __restrict__ attn,
                                            const uint16_t* __restrict__ wfcb,
                                            float* __restrict__ partial) {
    __shared__ uint16_t xh[8 * 4096];  // 64 KB
    int gimg = blockIdx.x;  // 0..31
    int kc = blockIdx.y;    // 0..15
    int b0 = gimg * 8;
    int K0 = kc * 4096;
    int tid = threadIdx.x;
    for (int j = tid; j < 8 * 4096; j += 256) {
        int im = j >> 12;
        int k = j & 4095;
        int gk = K0 + k;
        int s = gk & 1023;
        int bimg = b0 + im;
        float v = bf2f(pooled2[(((size_t)bimg) << 16) + gk]) * attn[((size_t)bimg << 10) + s];
        xh[j] = f2bf(v);
    }
    __syncthreads();

    int wv = tid >> 6, l = tid & 63;
    float acc[13][8];
#pragma unroll
    for (int j = 0; j < 13; ++j)
#pragma unroll
        for (int im = 0; im < 8; ++im) acc[j][im] = 0.f;

#pragma unroll 2
    for (int i = 0; i < 64; ++i) {
        int k = (i << 6) + l;
        float xv[8];
#pragma unroll
        for (int im = 0; im < 8; ++im) xv[im] = bf2f(xh[(im << 12) + k]);
#pragma unroll
        for (int j = 0; j < 13; ++j) {
            int o = wv + (j << 2);
            if (o < 50) {
                float w = bf2f(wfcb[(size_t)o * 65536 + K0 + k]);
#pragma unroll
                for (int im = 0; im < 8; ++im) acc[j][im] += w * xv[im];
            }
        }
    }
#pragma unroll
    for (int j = 0; j < 13; ++j) {
        int o = wv + (j << 2);
#pragma unroll
        for (int im = 0; im < 8; ++im) {
            float v = acc[j][im];
            for (int off = 32; off; off >>= 1) v += __shfl_xor(v, off);
            if (l == im && o < 50)
                partial[(((size_t)kc * 256 + (b0 + im)) << 6) + o] = v;
        }
    }
}

// ---------------------------------------------------------------------------
// Kernel E: MLP head + fusion. One wave per image.
// ---------------------------------------------------------------------------
__global__ __launch_bounds__(64) void k_head(const float* __restrict__ fbuf,
                                             const float* __restrict__ partial,
                                             const float* __restrict__ Wh1, const float* __restrict__ bh1,
                                             const float* __restrict__ Wh2, const float* __restrict__ bh2,
                                             const float* __restrict__ Wh3, const float* __restrict__ bh3,
                                             const float* __restrict__ bfc,
                                             const float* __restrict__ Wf, const float* __restrict__ bf_,
                                             const float* __restrict__ Wc, const float* __restrict__ bc,
                                             float* __restrict__ out) {
    __shared__ float fl[9];
    __shared__ float h1[32];
    __shared__ float h2[64];
    __shared__ float cat[100];
    int b = blockIdx.x;
    int l = threadIdx.x;
    if (l < 9) fl[l] = fbuf[b * 16 + l];
    __syncthreads();
    if (l < 32) {
        float a = bh1[l];
        for (int i = 0; i < 9; ++i) a += fl[i] * Wh1[l * 9 + i];
        h1[l] = fmaxf(a, 0.f);
    }
    __syncthreads();
    {
        float a = bh2[l];
        for (int i = 0; i < 32; ++i) a += h1[i] * Wh2[l * 32 + i];
        h2[l] = fmaxf(a, 0.f);
    }
    __syncthreads();
    if (l < 50) {
        float a = bh3[l];
        for (int i = 0; i < 64; ++i) a += h2[i] * Wh3[l * 64 + i];
        cat[50 + l] = fmaxf(a, 0.f);
        float s = bfc[l];
        for (int kc2 = 0; kc2 < 16; ++kc2) s += partial[(((size_t)kc2 * 256 + b) << 6) + l];
        cat[l] = fmaxf(s, 0.f);
    }
    __syncthreads();
    float a = bf_[l];
    for (int i = 0; i < 100; ++i) a += cat[i] * Wf[l * 100 + i];
    a = fmaxf(a, 0.f);
    float v = a * Wc[l];
    for (int off = 32; off; off >>= 1) v += __shfl_down(v, off);
    if (l == 0) out[b] = 1.f / (1.f + __expf(-(v + bc[0])));
}

// ---------------------------------------------------------------------------
extern "C" void kernel_launch(void* const* d_in, const int* in_sizes, int n_in,
                              void* d_out, int out_size, void* d_ws, size_t ws_size,
                              hipStream_t stream) {
    const float* images = (const float*)d_in[0];
    const float* W1 = (const float*)d_in[1];
    const float* b1 = (const float*)d_in[2];
    const float* W2 = (const float*)d_in[3];
    const float* b2 = (const float*)d_in[4];
    const float* Wa = (const float*)d_in[5];
    const float* ba = (const float*)d_in[6];
    const float* Wfc = (const float*)d_in[7];
    const float* bfc = (const float*)d_in[8];
    const float* Wh1 = (const float*)d_in[9];
    const float* bh1 = (const float*)d_in[10];
    const float* Wh2 = (const float*)d_in[11];
    const float* bh2 = (const float*)d_in[12];
    const float* Wh3 = (const float*)d_in[13];
    const float* bh3 = (const float*)d_in[14];
    const float* Wf = (const float*)d_in[15];
    const float* bf_ = (const float*)d_in[16];
    const float* Wc = (const float*)d_in[17];
    const float* bc = (const float*)d_in[18];

    // workspace layout (bytes)
    //   pooled1 bf16 NHWC [256,64,64,32] : 67108864   @ 0
    //   pooled2 bf16 NCHW [256,64,32,32] : 33554432   @ 67108864
    //   attn    f32  [256,32,32]         : 1048576    @ 100663296
    //   fbuf    f32  [256,16]            : 16384      @ 101711872
    //   partial f32  [16,256,64]         : 1048576    @ 101728256
    //   wA      bf16 [9,64,32]           : 36864      @ 102776832
    //   wfcb    bf16 [50,65536]          : aliases pooled1 (dead after conv2)
    const size_t NEEDED = 102813696;
    if (ws_size < NEEDED) return;

    char* ws = (char*)d_ws;
    uint16_t* pooled1 = (uint16_t*)ws;
    uint16_t* pooled2 = (uint16_t*)(ws + 67108864);
    float* attn = (float*)(ws + 100663296);
    float* fbuf = (float*)(ws + 101711872);
    float* partial = (float*)(ws + 101728256);
    uint16_t* wA = (uint16_t*)(ws + 102776832);
    uint16_t* wfcb = (uint16_t*)ws;  // alias pooled1
    float* out = (float*)d_out;

    hipLaunchKernelGGL(k_prep_w2, dim3(72), dim3(256), 0, stream, W2, wA);
    hipLaunchKernelGGL(k_handcrafted, dim3(3, 256), dim3(256), 0, stream, images, fbuf);
    hipLaunchKernelGGL(k_conv1, dim3(16, 256), dim3(256), 0, stream, images, W1, b1, pooled1);
    hipLaunchKernelGGL(k_conv2_mfma, dim3(16, 256), dim3(256), 0, stream, pooled1, wA, b2, pooled2);
    // pooled1 dead from here -> safe to overwrite with bf16 Wfc
    hipLaunchKernelGGL(k_prep_wfc, dim3(3200), dim3(256), 0, stream, Wfc, wfcb);
    hipLaunchKernelGGL(k_attn, dim3(256), dim3(256), 0, stream, pooled2, Wa, ba, attn);
    hipLaunchKernelGGL(k_fc, dim3(32, 16), dim3(256), 0, stream, pooled2, attn, wfcb, partial);
    hipLaunchKernelGGL(k_head, dim3(256), dim3(64), 0, stream, fbuf, partial,
                       Wh1, bh1, Wh2, bh2, Wh3, bh3, bfc, Wf, bf_, Wc, bc, out);
}

// Round 3
// 385.803 us; speedup vs baseline: 2.0208x; 1.3344x over previous
//
#include <hip/hip_runtime.h>
#include <stdint.h>

typedef __bf16 bf16x8 __attribute__((ext_vector_type(8)));
typedef float f32x4 __attribute__((ext_vector_type(4)));

// ---------- bf16 helpers ----------
__device__ inline float bf2f(uint16_t u) {
    uint32_t x = ((uint32_t)u) << 16;
    float f;
    __builtin_memcpy(&f, &x, 4);
    return f;
}
__device__ inline uint16_t f2bf(float f) {
    uint32_t x;
    __builtin_memcpy(&x, &f, 4);
    uint32_t r = (x + 0x7FFFu + ((x >> 16) & 1u)) >> 16;
    return (uint16_t)r;
}

// ---------------------------------------------------------------------------
// Weight prep: W2 [64][32][3][3] f32 -> wA [tap=9][oc=64][ic=32] bf16
// ---------------------------------------------------------------------------
__global__ __launch_bounds__(256) void k_prep_w2(const float* __restrict__ W2,
                                                 uint16_t* __restrict__ wA) {
    int j = blockIdx.x * 256 + threadIdx.x;
    if (j >= 18432) return;
    int t = j >> 11, rem = j & 2047, oc = rem >> 5, ic = rem & 31;
    int dy = t / 3, dx = t - dy * 3;
    wA[j] = f2bf(W2[(oc * 32 + ic) * 9 + dy * 3 + dx]);
}

// Wfc f32 -> bf16 (3,276,800 elems, 4 per thread)
__global__ __launch_bounds__(256) void k_prep_wfc(const float* __restrict__ Wfc,
                                                  uint16_t* __restrict__ wfcb) {
    int j = blockIdx.x * 256 + threadIdx.x;
    float4 v = ((const float4*)Wfc)[j];
    ushort4 o;
    o.x = f2bf(v.x);
    o.y = f2bf(v.y);
    o.z = f2bf(v.z);
    o.w = f2bf(v.w);
    ((ushort4*)wfcb)[j] = o;
}

// ---------------------------------------------------------------------------
// Kernel A: handcrafted features. One block per (channel, image).
// ---------------------------------------------------------------------------
__global__ __launch_bounds__(256) void k_handcrafted(const float* __restrict__ img,
                                                     float* __restrict__ f) {
    __shared__ float p[128 * 128];
    int c = blockIdx.x, b = blockIdx.y;
    const float* src = img + (((size_t)(b * 3 + c)) << 14);
    int tid = threadIdx.x;
    float sum = 0.f, sumsq = 0.f;
    for (int it = 0; it < 64; ++it) {
        int idx = tid + (it << 8);
        float v = floorf(src[idx] * 255.0f);
        p[idx] = v;
        sum += v;
        sumsq += v * v;
    }
    __syncthreads();
    float esum = 0.f;
    for (int it = 0; it < 64; ++it) {
        int idx = tid + (it << 8);
        int r = idx >> 7, cc = idx & 127;
        int rm = (r == 0) ? 1 : (r - 1), rp = (r == 127) ? 126 : (r + 1);
        int cm = (cc == 0) ? 1 : (cc - 1), cp = (cc == 127) ? 126 : (cc + 1);
        float a0 = p[(rm << 7) + cm], a1 = p[(rm << 7) + cc], a2 = p[(rm << 7) + cp];
        float b0 = p[(r << 7) + cm], b2 = p[(r << 7) + cp];
        float c0 = p[(rp << 7) + cm], c1 = p[(rp << 7) + cc], c2 = p[(rp << 7) + cp];
        float gx = (a2 - a0) + 2.f * (b2 - b0) + (c2 - c0);
        float gy = (c0 + 2.f * c1 + c2) - (a0 + 2.f * a1 + a2);
        esum += sqrtf(gx * gx + gy * gy);
    }
    for (int off = 32; off; off >>= 1) {
        sum += __shfl_down(sum, off);
        sumsq += __shfl_down(sumsq, off);
        esum += __shfl_down(esum, off);
    }
    __syncthreads();
    int w = tid >> 6;
    if ((tid & 63) == 0) {
        p[w * 3 + 0] = sum;
        p[w * 3 + 1] = sumsq;
        p[w * 3 + 2] = esum;
    }
    __syncthreads();
    if (tid == 0) {
        float S = 0.f, Q = 0.f, E = 0.f;
        for (int i = 0; i < 4; ++i) {
            S += p[i * 3 + 0];
            Q += p[i * 3 + 1];
            E += p[i * 3 + 2];
        }
        const float inv = 1.0f / 16384.0f;
        float mean = S * inv;
        float var = Q * inv - mean * mean;
        f[b * 16 + c] = E * inv;
        f[b * 16 + 3 + c] = mean;
        f[b * 16 + 6 + c] = sqrtf(fmaxf(var, 0.f));
    }
}

// ---------------------------------------------------------------------------
// Kernel B: conv1(3->32,3x3,pad1)+ReLU+maxpool2 -> pooled1 NHWC [B,64,64,32] bf16
// ---------------------------------------------------------------------------
__global__ __launch_bounds__(256) void k_conv1(const float* __restrict__ img,
                                               const float* __restrict__ W1,
                                               const float* __restrict__ b1,
                                               uint16_t* __restrict__ pooled1) {
    __shared__ float s_in[3 * 34 * 34];
    __shared__ float s_w[32 * 27];
    __shared__ float s_b[32];
    int tile = blockIdx.x;
    int b = blockIdx.y;
    int ty = tile >> 2, tx = tile & 3;
    int tid = threadIdx.x;
    int Y0 = ty * 32, X0 = tx * 32;
    for (int j = tid; j < 3 * 34 * 34; j += 256) {
        int ic = j / 1156;
        int rem = j - ic * 1156;
        int r = rem / 34, cc2 = rem - r * 34;
        int gy = Y0 - 1 + r, gx = X0 - 1 + cc2;
        float v = 0.f;
        if ((unsigned)gy < 128u && (unsigned)gx < 128u)
            v = img[(((size_t)b * 3 + ic) << 14) + (gy << 7) + gx];
        s_in[j] = v;
    }
    for (int j = tid; j < 864; j += 256) s_w[j] = W1[j];
    if (tid < 32) s_b[tid] = b1[tid];
    __syncthreads();

    int py = tid >> 4, px = tid & 15;
    float win[3][4][4];
#pragma unroll
    for (int ic = 0; ic < 3; ++ic)
#pragma unroll
        for (int r = 0; r < 4; ++r)
#pragma unroll
            for (int c2 = 0; c2 < 4; ++c2)
                win[ic][r][c2] = s_in[ic * 1156 + (2 * py + r) * 34 + 2 * px + c2];

    uint32_t packed[16];
#pragma unroll
    for (int op = 0; op < 16; ++op) {
        uint32_t pk = 0;
#pragma unroll
        for (int half = 0; half < 2; ++half) {
            int oc = 2 * op + half;
            float bb = s_b[oc];
            float a00 = bb, a01 = bb, a10 = bb, a11 = bb;
#pragma unroll
            for (int ic = 0; ic < 3; ++ic)
#pragma unroll
                for (int dy = 0; dy < 3; ++dy)
#pragma unroll
                    for (int dx = 0; dx < 3; ++dx) {
                        float w = s_w[((oc * 3 + ic) * 3 + dy) * 3 + dx];
                        a00 += w * win[ic][dy][dx];
                        a01 += w * win[ic][dy][dx + 1];
                        a10 += w * win[ic][dy + 1][dx];
                        a11 += w * win[ic][dy + 1][dx + 1];
                    }
            float m = fmaxf(fmaxf(a00, a01), fmaxf(a10, a11));
            m = fmaxf(m, 0.f);
            pk |= ((uint32_t)f2bf(m)) << (16 * half);
        }
        packed[op] = pk;
    }
    int Yp = ty * 16 + py, Xp = tx * 16 + px;
    uint4* dst = (uint4*)pooled1 + ((((size_t)b << 12) + (Yp << 6) + Xp) << 2);
#pragma unroll
    for (int q = 0; q < 4; ++q)
        dst[q] = make_uint4(packed[4 * q], packed[4 * q + 1], packed[4 * q + 2], packed[4 * q + 3]);
}

// ---------------------------------------------------------------------------
// Kernel C: conv2 via MFMA implicit GEMM (tap-decomposed, K=32 per tap).
// ---------------------------------------------------------------------------
__global__ __launch_bounds__(256) void k_conv2_mfma(const uint16_t* __restrict__ pooled1,
                                                    const uint16_t* __restrict__ wA,
                                                    const float* __restrict__ b2v,
                                                    uint16_t* __restrict__ pooled2) {
    __shared__ uint16_t s_in[10 * 34 * 32];   // 21760 B, row0 = conv row -1
    __shared__ uint16_t s_out[64 * 4 * 16];   // 8192 B
    const int bx = blockIdx.x;                // 0..15
    const int b = blockIdx.y;
    const int tx = bx >> 3, ty = bx & 7;
    const int X0 = tx * 32, Y0 = ty * 8;
    const int tid = threadIdx.x;

    for (int j = tid; j < 1360; j += 256) {
        int r = j / 136;
        int rem = j - r * 136;
        int px = rem >> 2, c4 = rem & 3;
        int gy = Y0 - 1 + r, gx = X0 - 1 + px;
        uint4 v = make_uint4(0, 0, 0, 0);
        if ((unsigned)gy < 64u && (unsigned)gx < 64u)
            v = ((const uint4*)pooled1)[((((size_t)b << 12) + gy * 64 + gx) << 2) + c4];
        *(uint4*)&s_in[(r * 34 + px) * 32 + c4 * 8] = v;
    }

    const int wv = tid >> 6, lane = tid & 63;
    const int ocq = wv & 1, xth = wv >> 1;
    const int rowl = lane & 15, kg = lane >> 4;

    bf16x8 afr[9][2];
#pragma unroll
    for (int t = 0; t < 9; ++t)
#pragma unroll
        for (int g = 0; g < 2; ++g)
            afr[t][g] = *(const bf16x8*)(wA + t * 2048 + (ocq * 32 + g * 16 + rowl) * 32 + kg * 8);
    float bias[2][4];
#pragma unroll
    for (int g = 0; g < 2; ++g)
#pragma unroll
        for (int r = 0; r < 4; ++r)
            bias[g][r] = b2v[ocq * 32 + g * 16 + kg * 4 + r];

    __syncthreads();

    for (int yp = 0; yp < 4; ++yp) {
        f32x4 acc[2][2];
#pragma unroll
        for (int p = 0; p < 2; ++p)
#pragma unroll
            for (int g = 0; g < 2; ++g)
#pragma unroll
                for (int r = 0; r < 4; ++r) acc[p][g][r] = bias[g][r];

        bf16x8 bfr[4][3];
#pragma unroll
        for (int rr = 0; rr < 4; ++rr)
#pragma unroll
            for (int dx = 0; dx < 3; ++dx) {
                int pix = (2 * yp + rr) * 34 + xth * 16 + rowl + dx;
                bfr[rr][dx] = *(const bf16x8*)(s_in + pix * 32 + kg * 8);
            }
#pragma unroll
        for (int dy = 0; dy < 3; ++dy)
#pragma unroll
            for (int dx = 0; dx < 3; ++dx) {
                int t = dy * 3 + dx;
#pragma unroll
                for (int g = 0; g < 2; ++g) {
                    acc[0][g] = __builtin_amdgcn_mfma_f32_16x16x32_bf16(afr[t][g], bfr[dy][dx], acc[0][g], 0, 0, 0);
                    acc[1][g] = __builtin_amdgcn_mfma_f32_16x16x32_bf16(afr[t][g], bfr[dy + 1][dx], acc[1][g], 0, 0, 0);
                }
            }
#pragma unroll
        for (int g = 0; g < 2; ++g)
#pragma unroll
            for (int r = 0; r < 4; ++r) {
                float m = fmaxf(acc[0][g][r], acc[1][g][r]);
                m = fmaxf(m, 0.f);
                float o = fmaxf(m, __shfl_xor(m, 1));
                if (!(lane & 1)) {
                    int oc = ocq * 32 + g * 16 + kg * 4 + r;
                    int px = xth * 8 + (rowl >> 1);
                    s_out[(oc * 4 + yp) * 16 + px] = f2bf(o);
                }
            }
    }
    __syncthreads();
    const int PY0 = ty * 4, PX0 = tx * 16;
    for (int j = tid; j < 512; j += 256) {
        int oc = j >> 3, py = (j >> 1) & 3, h = j & 1;
        uint4 v = *(const uint4*)&s_out[(oc * 4 + py) * 16 + h * 8];
        *(uint4*)&pooled2[(((size_t)b * 64 + oc) << 10) + (PY0 + py) * 32 + PX0 + h * 8] = v;
    }
}

// ---------------------------------------------------------------------------
// Kernel D1a: attention conv partials. Grid (8 ch-chunks, B). Each block
// covers 8 input channels for one image; partial conv into pattn.
// pattn layout: [cc][b][1024] f32
// ---------------------------------------------------------------------------
__global__ __launch_bounds__(256) void k_attn_part(const uint16_t* __restrict__ pooled2,
                                                   const float* __restrict__ Wa,
                                                   float* __restrict__ pattn) {
    __shared__ uint16_t s_in[8 * 38 * 38];  // 23104 B
    int cc = blockIdx.x;  // 0..7
    int b = blockIdx.y;
    int tid = threadIdx.x;
    for (int j = tid; j < 8 * 1444; j += 256) {
        int ch = j / 1444;
        int rem = j - ch * 1444;
        int r = rem / 38, c2 = rem - r * 38;
        int gy = r - 3, gx = c2 - 3;
        uint16_t v = 0;
        if ((unsigned)gy < 32u && (unsigned)gx < 32u)
            v = pooled2[(((size_t)b * 64 + cc * 8 + ch) << 10) + (gy << 5) + gx];
        s_in[j] = v;
    }
    __syncthreads();

    int y0 = (tid >> 4) * 2, x0 = (tid & 15) * 2;
    float acc[4] = {0.f, 0.f, 0.f, 0.f};
    for (int ch = 0; ch < 8; ++ch) {
        float win[8][8];
#pragma unroll
        for (int r = 0; r < 8; ++r)
#pragma unroll
            for (int cp = 0; cp < 4; ++cp) {
                uint32_t v = *(const uint32_t*)&s_in[ch * 1444 + (y0 + r) * 38 + x0 + 2 * cp];
                win[r][2 * cp] = bf2f((uint16_t)(v & 0xffffu));
                win[r][2 * cp + 1] = bf2f((uint16_t)(v >> 16));
            }
        const float* w = Wa + (cc * 8 + ch) * 49;
#pragma unroll
        for (int a = 0; a < 2; ++a)
#pragma unroll
            for (int bb = 0; bb < 2; ++bb) {
                float s = 0.f;
#pragma unroll
                for (int dy = 0; dy < 7; ++dy)
#pragma unroll
                    for (int dx = 0; dx < 7; ++dx)
                        s += w[dy * 7 + dx] * win[a + dy][bb + dx];
                acc[a * 2 + bb] += s;
            }
    }
#pragma unroll
    for (int a = 0; a < 2; ++a)
#pragma unroll
        for (int bb = 0; bb < 2; ++bb)
            pattn[(((size_t)cc * 256 + b) << 10) + ((y0 + a) << 5) + (x0 + bb)] = acc[a * 2 + bb];
}

// Kernel D1b: reduce 8 partials + bias + sigmoid -> attn [B,1024] f32
__global__ __launch_bounds__(256) void k_attn_reduce(const float* __restrict__ pattn,
                                                     const float* __restrict__ ba,
                                                     float* __restrict__ attn) {
    int b = blockIdx.x;
    int tid = threadIdx.x;
    float a0 = ba[0];
    float4 s = make_float4(a0, a0, a0, a0);
#pragma unroll
    for (int cc = 0; cc < 8; ++cc) {
        float4 v = ((const float4*)&pattn[(((size_t)cc * 256 + b) << 10)])[tid];
        s.x += v.x;
        s.y += v.y;
        s.z += v.z;
        s.w += v.w;
    }
    float4 o;
    o.x = 1.f / (1.f + __expf(-s.x));
    o.y = 1.f / (1.f + __expf(-s.y));
    o.z = 1.f / (1.f + __expf(-s.z));
    o.w = 1.f / (1.f + __expf(-s.w));
    ((float4*)&attn[((size_t)b << 10)])[tid] = o;
}

// ---------------------------------------------------------------------------
// Kernel D2: FC partials with bf16 weights.
// ---------------------------------------------------------------------------
__global__ __launch_bounds__(256) void k_fc(const uint16_t* __restrict__ pooled2,
                                            const float* __restrict__ attn,
                                            const uint16_t* __restrict__ wfcb,
                                            float* __restrict__ partial) {
    __shared__ uint16_t xh[8 * 4096];  // 64 KB
    int gimg = blockIdx.x;  // 0..31
    int kc = blockIdx.y;    // 0..15
    int b0 = gimg * 8;
    int K0 = kc * 4096;
    int tid = threadIdx.x;
    for (int j = tid; j < 8 * 4096; j += 256) {
        int im = j >> 12;
        int k = j & 4095;
        int gk = K0 + k;
        int s = gk & 1023;
        int bimg = b0 + im;
        float v = bf2f(pooled2[(((size_t)bimg) << 16) + gk]) * attn[((size_t)bimg << 10) + s];
        xh[j] = f2bf(v);
    }
    __syncthreads();

    int wv = tid >> 6, l = tid & 63;
    float acc[13][8];
#pragma unroll
    for (int j = 0; j < 13; ++j)
#pragma unroll
        for (int im = 0; im < 8; ++im) acc[j][im] = 0.f;

#pragma unroll 2
    for (int i = 0; i < 64; ++i) {
        int k = (i << 6) + l;
        float xv[8];
#pragma unroll
        for (int im = 0; im < 8; ++im) xv[im] = bf2f(xh[(im << 12) + k]);
#pragma unroll
        for (int j = 0; j < 13; ++j) {
            int o = wv + (j << 2);
            if (o < 50) {
                float w = bf2f(wfcb[(size_t)o * 65536 + K0 + k]);
#pragma unroll
                for (int im = 0; im < 8; ++im) acc[j][im] += w * xv[im];
            }
        }
    }
#pragma unroll
    for (int j = 0; j < 13; ++j) {
        int o = wv + (j << 2);
#pragma unroll
        for (int im = 0; im < 8; ++im) {
            float v = acc[j][im];
            for (int off = 32; off; off >>= 1) v += __shfl_xor(v, off);
            if (l == im && o < 50)
                partial[(((size_t)kc * 256 + (b0 + im)) << 6) + o] = v;
        }
    }
}

// ---------------------------------------------------------------------------
// Kernel E: MLP head + fusion. One wave per image.
// ---------------------------------------------------------------------------
__global__ __launch_bounds__(64) void k_head(const float* __restrict__ fbuf,
                                             const float* __restrict__ partial,
                                             const float* __restrict__ Wh1, const float* __restrict__ bh1,
                                             const float* __restrict__ Wh2, const float* __restrict__ bh2,
                                             const float* __restrict__ Wh3, const float* __restrict__ bh3,
                                             const float* __restrict__ bfc,
                                             const float* __restrict__ Wf, const float* __restrict__ bf_,
                                             const float* __restrict__ Wc, const float* __restrict__ bc,
                                             float* __restrict__ out) {
    __shared__ float fl[9];
    __shared__ float h1[32];
    __shared__ float h2[64];
    __shared__ float cat[100];
    int b = blockIdx.x;
    int l = threadIdx.x;
    if (l < 9) fl[l] = fbuf[b * 16 + l];
    __syncthreads();
    if (l < 32) {
        float a = bh1[l];
        for (int i = 0; i < 9; ++i) a += fl[i] * Wh1[l * 9 + i];
        h1[l] = fmaxf(a, 0.f);
    }
    __syncthreads();
    {
        float a = bh2[l];
        for (int i = 0; i < 32; ++i) a += h1[i] * Wh2[l * 32 + i];
        h2[l] = fmaxf(a, 0.f);
    }
    __syncthreads();
    if (l < 50) {
        float a = bh3[l];
        for (int i = 0; i < 64; ++i) a += h2[i] * Wh3[l * 64 + i];
        cat[50 + l] = fmaxf(a, 0.f);
        float s = bfc[l];
        for (int kc2 = 0; kc2 < 16; ++kc2) s += partial[(((size_t)kc2 * 256 + b) << 6) + l];
        cat[l] = fmaxf(s, 0.f);
    }
    __syncthreads();
    float a = bf_[l];
    for (int i = 0; i < 100; ++i) a += cat[i] * Wf[l * 100 + i];
    a = fmaxf(a, 0.f);
    float v = a * Wc[l];
    for (int off = 32; off; off >>= 1) v += __shfl_down(v, off);
    if (l == 0) out[b] = 1.f / (1.f + __expf(-(v + bc[0])));
}

// ---------------------------------------------------------------------------
extern "C" void kernel_launch(void* const* d_in, const int* in_sizes, int n_in,
                              void* d_out, int out_size, void* d_ws, size_t ws_size,
                              hipStream_t stream) {
    const float* images = (const float*)d_in[0];
    const float* W1 = (const float*)d_in[1];
    const float* b1 = (const float*)d_in[2];
    const float* W2 = (const float*)d_in[3];
    const float* b2 = (const float*)d_in[4];
    const float* Wa = (const float*)d_in[5];
    const float* ba = (const float*)d_in[6];
    const float* Wfc = (const float*)d_in[7];
    const float* bfc = (const float*)d_in[8];
    const float* Wh1 = (const float*)d_in[9];
    const float* bh1 = (const float*)d_in[10];
    const float* Wh2 = (const float*)d_in[11];
    const float* bh2 = (const float*)d_in[12];
    const float* Wh3 = (const float*)d_in[13];
    const float* bh3 = (const float*)d_in[14];
    const float* Wf = (const float*)d_in[15];
    const float* bf_ = (const float*)d_in[16];
    const float* Wc = (const float*)d_in[17];
    const float* bc = (const float*)d_in[18];

    // workspace layout (bytes)
    //   pooled1 bf16 NHWC [256,64,64,32] : 67108864   @ 0
    //     after conv2, this region is dead and re-used as:
    //       wfcb  bf16 [50,65536]        : 6553600    @ 0
    //       pattn f32  [8,256,1024]      : 8388608    @ 8388608
    //   pooled2 bf16 NCHW [256,64,32,32] : 33554432   @ 67108864
    //   attn    f32  [256,32,32]         : 1048576    @ 100663296
    //   fbuf    f32  [256,16]            : 16384      @ 101711872
    //   partial f32  [16,256,64]         : 1048576    @ 101728256
    //   wA      bf16 [9,64,32]           : 36864      @ 102776832
    const size_t NEEDED = 102813696;
    if (ws_size < NEEDED) return;

    char* ws = (char*)d_ws;
    uint16_t* pooled1 = (uint16_t*)ws;
    uint16_t* pooled2 = (uint16_t*)(ws + 67108864);
    float* attn = (float*)(ws + 100663296);
    float* fbuf = (float*)(ws + 101711872);
    float* partial = (float*)(ws + 101728256);
    uint16_t* wA = (uint16_t*)(ws + 102776832);
    uint16_t* wfcb = (uint16_t*)ws;           // alias pooled1 (dead after conv2)
    float* pattn = (float*)(ws + 8388608);    // alias pooled1 tail (dead after conv2)
    float* out = (float*)d_out;

    hipLaunchKernelGGL(k_prep_w2, dim3(72), dim3(256), 0, stream, W2, wA);
    hipLaunchKernelGGL(k_handcrafted, dim3(3, 256), dim3(256), 0, stream, images, fbuf);
    hipLaunchKernelGGL(k_conv1, dim3(16, 256), dim3(256), 0, stream, images, W1, b1, pooled1);
    hipLaunchKernelGGL(k_conv2_mfma, dim3(16, 256), dim3(256), 0, stream, pooled1, wA, b2, pooled2);
    // pooled1 dead from here
    hipLaunchKernelGGL(k_prep_wfc, dim3(3200), dim3(256), 0, stream, Wfc, wfcb);
    hipLaunchKernelGGL(k_attn_part, dim3(8, 256), dim3(256), 0, stream, pooled2, Wa, pattn);
    hipLaunchKernelGGL(k_attn_reduce, dim3(256), dim3(256), 0, stream, pattn, ba, attn);
    hipLaunchKernelGGL(k_fc, dim3(32, 16), dim3(256), 0, stream, pooled2, attn, wfcb, partial);
    hipLaunchKernelGGL(k_head, dim3(256), dim3(64), 0, stream, fbuf, partial,
                       Wh1, bh1, Wh2, bh2, Wh3, bh3, bfc, Wf, bf_, Wc, bc, out);
}

// Round 4
// 342.548 us; speedup vs baseline: 2.2760x; 1.1263x over previous
//
#include <hip/hip_runtime.h>
#include <stdint.h>

typedef __bf16 bf16x8 __attribute__((ext_vector_type(8)));
typedef float f32x4 __attribute__((ext_vector_type(4)));

// ---------- bf16 helpers ----------
__device__ inline float bf2f(uint16_t u) {
    uint32_t x = ((uint32_t)u) << 16;
    float f;
    __builtin_memcpy(&f, &x, 4);
    return f;
}
__device__ inline uint16_t f2bf(float f) {
    uint32_t x;
    __builtin_memcpy(&x, &f, 4);
    uint32_t r = (x + 0x7FFFu + ((x >> 16) & 1u)) >> 16;
    return (uint16_t)r;
}

// ---------------------------------------------------------------------------
// Weight prep: W2 [64][32][3][3] f32 -> wA [tap=9][oc=64][ic=32] bf16
// ---------------------------------------------------------------------------
__global__ __launch_bounds__(256) void k_prep_w2(const float* __restrict__ W2,
                                                 uint16_t* __restrict__ wA) {
    int j = blockIdx.x * 256 + threadIdx.x;
    if (j >= 18432) return;
    int t = j >> 11, rem = j & 2047, oc = rem >> 5, ic = rem & 31;
    int dy = t / 3, dx = t - dy * 3;
    wA[j] = f2bf(W2[(oc * 32 + ic) * 9 + dy * 3 + dx]);
}

// W1 [32][3][3][3] f32 -> wA1 [oc=32][k=32] bf16, k = ic*9+dy*3+dx, k>=27 -> 0
__global__ __launch_bounds__(256) void k_prep_w1(const float* __restrict__ W1,
                                                 uint16_t* __restrict__ wA1) {
    int j = blockIdx.x * 256 + threadIdx.x;
    if (j >= 1024) return;
    int oc = j >> 5, k = j & 31;
    wA1[j] = (k < 27) ? f2bf(W1[oc * 27 + k]) : (uint16_t)0;
}

// Wfc f32 -> bf16 (3,276,800 elems, 4 per thread)
__global__ __launch_bounds__(256) void k_prep_wfc(const float* __restrict__ Wfc,
                                                  uint16_t* __restrict__ wfcb) {
    int j = blockIdx.x * 256 + threadIdx.x;
    float4 v = ((const float4*)Wfc)[j];
    ushort4 o;
    o.x = f2bf(v.x);
    o.y = f2bf(v.y);
    o.z = f2bf(v.z);
    o.w = f2bf(v.w);
    ((ushort4*)wfcb)[j] = o;
}

// ---------------------------------------------------------------------------
// Kernel A: handcrafted features. One block per (channel, image).
// ---------------------------------------------------------------------------
__global__ __launch_bounds__(256) void k_handcrafted(const float* __restrict__ img,
                                                     float* __restrict__ f) {
    __shared__ float p[128 * 128];
    int c = blockIdx.x, b = blockIdx.y;
    const float* src = img + (((size_t)(b * 3 + c)) << 14);
    int tid = threadIdx.x;
    float sum = 0.f, sumsq = 0.f;
    for (int it = 0; it < 64; ++it) {
        int idx = tid + (it << 8);
        float v = floorf(src[idx] * 255.0f);
        p[idx] = v;
        sum += v;
        sumsq += v * v;
    }
    __syncthreads();
    float esum = 0.f;
    for (int it = 0; it < 64; ++it) {
        int idx = tid + (it << 8);
        int r = idx >> 7, cc = idx & 127;
        int rm = (r == 0) ? 1 : (r - 1), rp = (r == 127) ? 126 : (r + 1);
        int cm = (cc == 0) ? 1 : (cc - 1), cp = (cc == 127) ? 126 : (cc + 1);
        float a0 = p[(rm << 7) + cm], a1 = p[(rm << 7) + cc], a2 = p[(rm << 7) + cp];
        float b0 = p[(r << 7) + cm], b2 = p[(r << 7) + cp];
        float c0 = p[(rp << 7) + cm], c1 = p[(rp << 7) + cc], c2 = p[(rp << 7) + cp];
        float gx = (a2 - a0) + 2.f * (b2 - b0) + (c2 - c0);
        float gy = (c0 + 2.f * c1 + c2) - (a0 + 2.f * a1 + a2);
        esum += sqrtf(gx * gx + gy * gy);
    }
    for (int off = 32; off; off >>= 1) {
        sum += __shfl_down(sum, off);
        sumsq += __shfl_down(sumsq, off);
        esum += __shfl_down(esum, off);
    }
    __syncthreads();
    int w = tid >> 6;
    if ((tid & 63) == 0) {
        p[w * 3 + 0] = sum;
        p[w * 3 + 1] = sumsq;
        p[w * 3 + 2] = esum;
    }
    __syncthreads();
    if (tid == 0) {
        float S = 0.f, Q = 0.f, E = 0.f;
        for (int i = 0; i < 4; ++i) {
            S += p[i * 3 + 0];
            Q += p[i * 3 + 1];
            E += p[i * 3 + 2];
        }
        const float inv = 1.0f / 16384.0f;
        float mean = S * inv;
        float var = Q * inv - mean * mean;
        f[b * 16 + c] = E * inv;
        f[b * 16 + 3 + c] = mean;
        f[b * 16 + 6 + c] = sqrtf(fmaxf(var, 0.f));
    }
}

// ---------------------------------------------------------------------------
// Kernel B: conv1 via MFMA implicit GEMM. K=32 (27 taps zero-padded),
// M=32 oc (2 groups of 16), N=16 pixels. B-frags assembled per-lane from the
// staged fp32 tile with 8 precomputed tap offsets (k>=27 -> offset 0, A=0).
// Block = 256 thr = 4 waves; tile = 32x32 conv = 16x16 pooled; grid (16, B).
// Output pooled1 NHWC [B,64,64,32] bf16.
// ---------------------------------------------------------------------------
__global__ __launch_bounds__(256) void k_conv1_mfma(const float* __restrict__ img,
                                                    const uint16_t* __restrict__ wA1,
                                                    const float* __restrict__ b1,
                                                    uint16_t* __restrict__ pooled1) {
    __shared__ float s_in[3 * 34 * 34];      // 13872 B, origin at (Y0-1, X0-1)
    __shared__ uint16_t s_out[16 * 16 * 32]; // 16384 B: [py][px][oc]
    const int tile = blockIdx.x;
    const int b = blockIdx.y;
    const int ty = tile >> 2, tx = tile & 3;
    const int Y0 = ty * 32, X0 = tx * 32;
    const int tid = threadIdx.x;

    // stage input tile (3 ic x 34 x 34), zero outside image
    for (int j = tid; j < 3 * 1156; j += 256) {
        int ic = j / 1156;
        int rem = j - ic * 1156;
        int r = rem / 34, cc2 = rem - r * 34;
        int gy = Y0 - 1 + r, gx = X0 - 1 + cc2;
        float v = 0.f;
        if ((unsigned)gy < 128u && (unsigned)gx < 128u)
            v = img[(((size_t)b * 3 + ic) << 14) + (gy << 7) + gx];
        s_in[j] = v;
    }

    const int wv = tid >> 6, lane = tid & 63;
    const int rowl = lane & 15, kg = lane >> 4;

    // per-lane tap offsets for this lane's k-slice (k = kg*8 + i)
    int off[8];
#pragma unroll
    for (int i = 0; i < 8; ++i) {
        int k = kg * 8 + i;
        int ic = (k * 57) >> 9;        // k/9 for k<32
        int rem = k - 9 * ic;
        int dy = (rem * 11) >> 5;      // rem/3
        int dx = rem - 3 * dy;
        off[i] = (k < 27) ? (ic * 1156 + dy * 34 + dx) : 0;
    }

    // A fragments (weights) + bias
    bf16x8 afr[2];
#pragma unroll
    for (int g = 0; g < 2; ++g)
        afr[g] = *(const bf16x8*)(wA1 + (g * 16 + rowl) * 32 + kg * 8);
    float bias[2][4];
#pragma unroll
    for (int g = 0; g < 2; ++g)
#pragma unroll
        for (int r = 0; r < 4; ++r)
            bias[g][r] = b1[g * 16 + kg * 4 + r];

    __syncthreads();

    // wave wv owns conv rows wv*8 .. wv*8+7 -> pooled rows wv*4 .. +3
    for (int rp = 0; rp < 4; ++rp) {
#pragma unroll
        for (int seg = 0; seg < 2; ++seg) {
            f32x4 acc[2][2];
#pragma unroll
            for (int rr = 0; rr < 2; ++rr)
#pragma unroll
                for (int g = 0; g < 2; ++g)
#pragma unroll
                    for (int r = 0; r < 4; ++r) acc[rr][g][r] = bias[g][r];

#pragma unroll
            for (int rr = 0; rr < 2; ++rr) {
                int ly = wv * 8 + rp * 2 + rr;
                int base = ly * 34 + seg * 16 + rowl;
                float v[8];
#pragma unroll
                for (int i = 0; i < 8; ++i) v[i] = s_in[base + off[i]];
                bf16x8 bf;
#pragma unroll
                for (int i = 0; i < 8; ++i) bf[i] = (__bf16)v[i];
#pragma unroll
                for (int g = 0; g < 2; ++g)
                    acc[rr][g] = __builtin_amdgcn_mfma_f32_16x16x32_bf16(afr[g], bf, acc[rr][g], 0, 0, 0);
            }
            // pool 2x2 + relu; C/D: col(=x)=lane&15, row(=oc)=kg*4+r
#pragma unroll
            for (int g = 0; g < 2; ++g)
#pragma unroll
                for (int r = 0; r < 4; ++r) {
                    float m = fmaxf(acc[0][g][r], acc[1][g][r]);
                    m = fmaxf(m, 0.f);
                    float o = fmaxf(m, __shfl_xor(m, 1));
                    if (!(lane & 1)) {
                        int py = wv * 4 + rp;
                        int px = seg * 8 + (rowl >> 1);
                        int oc = g * 16 + kg * 4 + r;
                        s_out[(py * 16 + px) * 32 + oc] = f2bf(o);
                    }
                }
        }
    }
    __syncthreads();
    // coalesced NHWC store: pooled rows ty*16.., cols tx*16..; 64B per pixel
    {
        int py = tid >> 4, px = tid & 15;
        const uint4* src = (const uint4*)&s_out[tid * 32];
        uint4* dst = (uint4*)pooled1 +
                     ((((size_t)b << 12) + (ty * 16 + py) * 64 + tx * 16 + px) << 2);
#pragma unroll
        for (int q = 0; q < 4; ++q) dst[q] = src[q];
    }
}

// ---------------------------------------------------------------------------
// Kernel C: conv2 via MFMA implicit GEMM (tap-decomposed, K=32 per tap).
// ---------------------------------------------------------------------------
__global__ __launch_bounds__(256) void k_conv2_mfma(const uint16_t* __restrict__ pooled1,
                                                    const uint16_t* __restrict__ wA,
                                                    const float* __restrict__ b2v,
                                                    uint16_t* __restrict__ pooled2) {
    __shared__ uint16_t s_in[10 * 34 * 32];   // 21760 B, row0 = conv row -1
    __shared__ uint16_t s_out[64 * 4 * 16];   // 8192 B
    const int bx = blockIdx.x;                // 0..15
    const int b = blockIdx.y;
    const int tx = bx >> 3, ty = bx & 7;
    const int X0 = tx * 32, Y0 = ty * 8;
    const int tid = threadIdx.x;

    for (int j = tid; j < 1360; j += 256) {
        int r = j / 136;
        int rem = j - r * 136;
        int px = rem >> 2, c4 = rem & 3;
        int gy = Y0 - 1 + r, gx = X0 - 1 + px;
        uint4 v = make_uint4(0, 0, 0, 0);
        if ((unsigned)gy < 64u && (unsigned)gx < 64u)
            v = ((const uint4*)pooled1)[((((size_t)b << 12) + gy * 64 + gx) << 2) + c4];
        *(uint4*)&s_in[(r * 34 + px) * 32 + c4 * 8] = v;
    }

    const int wv = tid >> 6, lane = tid & 63;
    const int ocq = wv & 1, xth = wv >> 1;
    const int rowl = lane & 15, kg = lane >> 4;

    bf16x8 afr[9][2];
#pragma unroll
    for (int t = 0; t < 9; ++t)
#pragma unroll
        for (int g = 0; g < 2; ++g)
            afr[t][g] = *(const bf16x8*)(wA + t * 2048 + (ocq * 32 + g * 16 + rowl) * 32 + kg * 8);
    float bias[2][4];
#pragma unroll
    for (int g = 0; g < 2; ++g)
#pragma unroll
        for (int r = 0; r < 4; ++r)
            bias[g][r] = b2v[ocq * 32 + g * 16 + kg * 4 + r];

    __syncthreads();

    for (int yp = 0; yp < 4; ++yp) {
        f32x4 acc[2][2];
#pragma unroll
        for (int p = 0; p < 2; ++p)
#pragma unroll
            for (int g = 0; g < 2; ++g)
#pragma unroll
                for (int r = 0; r < 4; ++r) acc[p][g][r] = bias[g][r];

        bf16x8 bfr[4][3];
#pragma unroll
        for (int rr = 0; rr < 4; ++rr)
#pragma unroll
            for (int dx = 0; dx < 3; ++dx) {
                int pix = (2 * yp + rr) * 34 + xth * 16 + rowl + dx;
                bfr[rr][dx] = *(const bf16x8*)(s_in + pix * 32 + kg * 8);
            }
#pragma unroll
        for (int dy = 0; dy < 3; ++dy)
#pragma unroll
            for (int dx = 0; dx < 3; ++dx) {
                int t = dy * 3 + dx;
#pragma unroll
                for (int g = 0; g < 2; ++g) {
                    acc[0][g] = __builtin_amdgcn_mfma_f32_16x16x32_bf16(afr[t][g], bfr[dy][dx], acc[0][g], 0, 0, 0);
                    acc[1][g] = __builtin_amdgcn_mfma_f32_16x16x32_bf16(afr[t][g], bfr[dy + 1][dx], acc[1][g], 0, 0, 0);
                }
            }
#pragma unroll
        for (int g = 0; g < 2; ++g)
#pragma unroll
            for (int r = 0; r < 4; ++r) {
                float m = fmaxf(acc[0][g][r], acc[1][g][r]);
                m = fmaxf(m, 0.f);
                float o = fmaxf(m, __shfl_xor(m, 1));
                if (!(lane & 1)) {
                    int oc = ocq * 32 + g * 16 + kg * 4 + r;
                    int px = xth * 8 + (rowl >> 1);
                    s_out[(oc * 4 + yp) * 16 + px] = f2bf(o);
                }
            }
    }
    __syncthreads();
    const int PY0 = ty * 4, PX0 = tx * 16;
    for (int j = tid; j < 512; j += 256) {
        int oc = j >> 3, py = (j >> 1) & 3, h = j & 1;
        uint4 v = *(const uint4*)&s_out[(oc * 4 + py) * 16 + h * 8];
        *(uint4*)&pooled2[(((size_t)b * 64 + oc) << 10) + (PY0 + py) * 32 + PX0 + h * 8] = v;
    }
}

// ---------------------------------------------------------------------------
// Kernel D1a: attention conv partials. Grid (8 ch-chunks, B).
// pattn layout: [cc][b][1024] f32
// ---------------------------------------------------------------------------
__global__ __launch_bounds__(256) void k_attn_part(const uint16_t* __restrict__ pooled2,
                                                   const float* __restrict__ Wa,
                                                   float* __restrict__ pattn) {
    __shared__ uint16_t s_in[8 * 38 * 38];  // 23104 B
    int cc = blockIdx.x;  // 0..7
    int b = blockIdx.y;
    int tid = threadIdx.x;
    for (int j = tid; j < 8 * 1444; j += 256) {
        int ch = j / 1444;
        int rem = j - ch * 1444;
        int r = rem / 38, c2 = rem - r * 38;
        int gy = r - 3, gx = c2 - 3;
        uint16_t v = 0;
        if ((unsigned)gy < 32u && (unsigned)gx < 32u)
            v = pooled2[(((size_t)b * 64 + cc * 8 + ch) << 10) + (gy << 5) + gx];
        s_in[j] = v;
    }
    __syncthreads();

    int y0 = (tid >> 4) * 2, x0 = (tid & 15) * 2;
    float acc[4] = {0.f, 0.f, 0.f, 0.f};
    for (int ch = 0; ch < 8; ++ch) {
        float win[8][8];
#pragma unroll
        for (int r = 0; r < 8; ++r)
#pragma unroll
            for (int cp = 0; cp < 4; ++cp) {
                uint32_t v = *(const uint32_t*)&s_in[ch * 1444 + (y0 + r) * 38 + x0 + 2 * cp];
                win[r][2 * cp] = bf2f((uint16_t)(v & 0xffffu));
                win[r][2 * cp + 1] = bf2f((uint16_t)(v >> 16));
            }
        const float* w = Wa + (cc * 8 + ch) * 49;
#pragma unroll
        for (int a = 0; a < 2; ++a)
#pragma unroll
            for (int bb = 0; bb < 2; ++bb) {
                float s = 0.f;
#pragma unroll
                for (int dy = 0; dy < 7; ++dy)
#pragma unroll
                    for (int dx = 0; dx < 7; ++dx)
                        s += w[dy * 7 + dx] * win[a + dy][bb + dx];
                acc[a * 2 + bb] += s;
            }
    }
#pragma unroll
    for (int a = 0; a < 2; ++a)
#pragma unroll
        for (int bb = 0; bb < 2; ++bb)
            pattn[(((size_t)cc * 256 + b) << 10) + ((y0 + a) << 5) + (x0 + bb)] = acc[a * 2 + bb];
}

// Kernel D1b: reduce 8 partials + bias + sigmoid -> attn [B,1024] f32
__global__ __launch_bounds__(256) void k_attn_reduce(const float* __restrict__ pattn,
                                                     const float* __restrict__ ba,
                                                     float* __restrict__ attn) {
    int b = blockIdx.x;
    int tid = threadIdx.x;
    float a0 = ba[0];
    float4 s = make_float4(a0, a0, a0, a0);
#pragma unroll
    for (int cc = 0; cc < 8; ++cc) {
        float4 v = ((const float4*)&pattn[(((size_t)cc * 256 + b) << 10)])[tid];
        s.x += v.x;
        s.y += v.y;
        s.z += v.z;
        s.w += v.w;
    }
    float4 o;
    o.x = 1.f / (1.f + __expf(-s.x));
    o.y = 1.f / (1.f + __expf(-s.y));
    o.z = 1.f / (1.f + __expf(-s.z));
    o.w = 1.f / (1.f + __expf(-s.w));
    ((float4*)&attn[((size_t)b << 10)])[tid] = o;
}

// ---------------------------------------------------------------------------
// Kernel D2: FC partials with bf16 weights.
// ---------------------------------------------------------------------------
__global__ __launch_bounds__(256) void k_fc(const uint16_t* __restrict__ pooled2,
                                            const float* __restrict__ attn,
                                            const uint16_t* __restrict__ wfcb,
                                            float* __restrict__ partial) {
    __shared__ uint16_t xh[8 * 4096];  // 64 KB
    int gimg = blockIdx.x;  // 0..31
    int kc = blockIdx.y;    // 0..15
    int b0 = gimg * 8;
    int K0 = kc * 4096;
    int tid = threadIdx.x;
    for (int j = tid; j < 8 * 4096; j += 256) {
        int im = j >> 12;
        int k = j & 4095;
        int gk = K0 + k;
        int s = gk & 1023;
        int bimg = b0 + im;
        float v = bf2f(pooled2[(((size_t)bimg) << 16) + gk]) * attn[((size_t)bimg << 10) + s];
        xh[j] = f2bf(v);
    }
    __syncthreads();

    int wv = tid >> 6, l = tid & 63;
    float acc[13][8];
#pragma unroll
    for (int j = 0; j < 13; ++j)
#pragma unroll
        for (int im = 0; im < 8; ++im) acc[j][im] = 0.f;

#pragma unroll 2
    for (int i = 0; i < 64; ++i) {
        int k = (i << 6) + l;
        float xv[8];
#pragma unroll
        for (int im = 0; im < 8; ++im) xv[im] = bf2f(xh[(im << 12) + k]);
#pragma unroll
        for (int j = 0; j < 13; ++j) {
            int o = wv + (j << 2);
            if (o < 50) {
                float w = bf2f(wfcb[(size_t)o * 65536 + K0 + k]);
#pragma unroll
                for (int im = 0; im < 8; ++im) acc[j][im] += w * xv[im];
            }
        }
    }
#pragma unroll
    for (int j = 0; j < 13; ++j) {
        int o = wv + (j << 2);
#pragma unroll
        for (int im = 0; im < 8; ++im) {
            float v = acc[j][im];
            for (int off = 32; off; off >>= 1) v += __shfl_xor(v, off);
            if (l == im && o < 50)
                partial[(((size_t)kc * 256 + (b0 + im)) << 6) + o] = v;
        }
    }
}

// ---------------------------------------------------------------------------
// Kernel E: MLP head + fusion. One wave per image.
// ---------------------------------------------------------------------------
__global__ __launch_bounds__(64) void k_head(const float* __restrict__ fbuf,
                                             const float* __restrict__ partial,
                                             const float* __restrict__ Wh1, const float* __restrict__ bh1,
                                             const float* __restrict__ Wh2, const float* __restrict__ bh2,
                                             const float* __restrict__ Wh3, const float* __restrict__ bh3,
                                             const float* __restrict__ bfc,
                                             const float* __restrict__ Wf, const float* __restrict__ bf_,
                                             const float* __restrict__ Wc, const float* __restrict__ bc,
                                             float* __restrict__ out) {
    __shared__ float fl[9];
    __shared__ float h1[32];
    __shared__ float h2[64];
    __shared__ float cat[100];
    int b = blockIdx.x;
    int l = threadIdx.x;
    if (l < 9) fl[l] = fbuf[b * 16 + l];
    __syncthreads();
    if (l < 32) {
        float a = bh1[l];
        for (int i = 0; i < 9; ++i) a += fl[i] * Wh1[l * 9 + i];
        h1[l] = fmaxf(a, 0.f);
    }
    __syncthreads();
    {
        float a = bh2[l];
        for (int i = 0; i < 32; ++i) a += h1[i] * Wh2[l * 32 + i];
        h2[l] = fmaxf(a, 0.f);
    }
    __syncthreads();
    if (l < 50) {
        float a = bh3[l];
        for (int i = 0; i < 64; ++i) a += h2[i] * Wh3[l * 64 + i];
        cat[50 + l] = fmaxf(a, 0.f);
        float s = bfc[l];
        for (int kc2 = 0; kc2 < 16; ++kc2) s += partial[(((size_t)kc2 * 256 + b) << 6) + l];
        cat[l] = fmaxf(s, 0.f);
    }
    __syncthreads();
    float a = bf_[l];
    for (int i = 0; i < 100; ++i) a += cat[i] * Wf[l * 100 + i];
    a = fmaxf(a, 0.f);
    float v = a * Wc[l];
    for (int off = 32; off; off >>= 1) v += __shfl_down(v, off);
    if (l == 0) out[b] = 1.f / (1.f + __expf(-(v + bc[0])));
}

// ---------------------------------------------------------------------------
extern "C" void kernel_launch(void* const* d_in, const int* in_sizes, int n_in,
                              void* d_out, int out_size, void* d_ws, size_t ws_size,
                              hipStream_t stream) {
    const float* images = (const float*)d_in[0];
    const float* W1 = (const float*)d_in[1];
    const float* b1 = (const float*)d_in[2];
    const float* W2 = (const float*)d_in[3];
    const float* b2 = (const float*)d_in[4];
    const float* Wa = (const float*)d_in[5];
    const float* ba = (const float*)d_in[6];
    const float* Wfc = (const float*)d_in[7];
    const float* bfc = (const float*)d_in[8];
    const float* Wh1 = (const float*)d_in[9];
    const float* bh1 = (const float*)d_in[10];
    const float* Wh2 = (const float*)d_in[11];
    const float* bh2 = (const float*)d_in[12];
    const float* Wh3 = (const float*)d_in[13];
    const float* bh3 = (const float*)d_in[14];
    const float* Wf = (const float*)d_in[15];
    const float* bf_ = (const float*)d_in[16];
    const float* Wc = (const float*)d_in[17];
    const float* bc = (const float*)d_in[18];

    // workspace layout (bytes)
    //   pooled1 bf16 NHWC [256,64,64,32] : 67108864   @ 0
    //     after conv2, this region is dead and re-used as:
    //       wfcb  bf16 [50,65536]        : 6553600    @ 0
    //       pattn f32  [8,256,1024]      : 8388608    @ 8388608
    //   pooled2 bf16 NCHW [256,64,32,32] : 33554432   @ 67108864
    //   attn    f32  [256,32,32]         : 1048576    @ 100663296
    //   fbuf    f32  [256,16]            : 16384      @ 101711872
    //   partial f32  [16,256,64]         : 1048576    @ 101728256
    //   wA      bf16 [9,64,32]           : 36864      @ 102776832
    //   wA1     bf16 [32,32]             : 2048       @ 102813696
    const size_t NEEDED = 102815744;
    if (ws_size < NEEDED) return;

    char* ws = (char*)d_ws;
    uint16_t* pooled1 = (uint16_t*)ws;
    uint16_t* pooled2 = (uint16_t*)(ws + 67108864);
    float* attn = (float*)(ws + 100663296);
    float* fbuf = (float*)(ws + 101711872);
    float* partial = (float*)(ws + 101728256);
    uint16_t* wA = (uint16_t*)(ws + 102776832);
    uint16_t* wA1 = (uint16_t*)(ws + 102813696);
    uint16_t* wfcb = (uint16_t*)ws;           // alias pooled1 (dead after conv2)
    float* pattn = (float*)(ws + 8388608);    // alias pooled1 tail (dead after conv2)
    float* out = (float*)d_out;

    hipLaunchKernelGGL(k_prep_w2, dim3(72), dim3(256), 0, stream, W2, wA);
    hipLaunchKernelGGL(k_prep_w1, dim3(4), dim3(256), 0, stream, W1, wA1);
    hipLaunchKernelGGL(k_handcrafted, dim3(3, 256), dim3(256), 0, stream, images, fbuf);
    hipLaunchKernelGGL(k_conv1_mfma, dim3(16, 256), dim3(256), 0, stream, images, wA1, b1, pooled1);
    hipLaunchKernelGGL(k_conv2_mfma, dim3(16, 256), dim3(256), 0, stream, pooled1, wA, b2, pooled2);
    // pooled1 dead from here
    hipLaunchKernelGGL(k_prep_wfc, dim3(3200), dim3(256), 0, stream, Wfc, wfcb);
    hipLaunchKernelGGL(k_attn_part, dim3(8, 256), dim3(256), 0, stream, pooled2, Wa, pattn);
    hipLaunchKernelGGL(k_attn_reduce, dim3(256), dim3(256), 0, stream, pattn, ba, attn);
    hipLaunchKernelGGL(k_fc, dim3(32, 16), dim3(256), 0, stream, pooled2, attn, wfcb, partial);
    hipLaunchKernelGGL(k_head, dim3(256), dim3(64), 0, stream, fbuf, partial,
                       Wh1, bh1, Wh2, bh2, Wh3, bh3, bfc, Wf, bf_, Wc, bc, out);
}

// Round 5
// 238.316 us; speedup vs baseline: 3.2714x; 1.4374x over previous
//
#include <hip/hip_runtime.h>
#include <stdint.h>

typedef __bf16 bf16x8 __attribute__((ext_vector_type(8)));
typedef float f32x4 __attribute__((ext_vector_type(4)));

// ---------- bf16 helpers ----------
__device__ inline float bf2f(uint16_t u) {
    uint32_t x = ((uint32_t)u) << 16;
    float f;
    __builtin_memcpy(&f, &x, 4);
    return f;
}
__device__ inline uint16_t f2bf(float f) {
    uint32_t x;
    __builtin_memcpy(&x, &f, 4);
    uint32_t r = (x + 0x7FFFu + ((x >> 16) & 1u)) >> 16;
    return (uint16_t)r;
}

// ---------------------------------------------------------------------------
// Weight prep: W2 [64][32][3][3] f32 -> wA [tap=9][oc=64][ic=32] bf16
// ---------------------------------------------------------------------------
__global__ __launch_bounds__(256) void k_prep_w2(const float* __restrict__ W2,
                                                 uint16_t* __restrict__ wA) {
    int j = blockIdx.x * 256 + threadIdx.x;
    if (j >= 18432) return;
    int t = j >> 11, rem = j & 2047, oc = rem >> 5, ic = rem & 31;
    int dy = t / 3, dx = t - dy * 3;
    wA[j] = f2bf(W2[(oc * 32 + ic) * 9 + dy * 3 + dx]);
}

// W1 [32][3][3][3] f32 -> wA1 [oc=32][k=32] bf16, k = ic*9+dy*3+dx, k>=27 -> 0
__global__ __launch_bounds__(256) void k_prep_w1(const float* __restrict__ W1,
                                                 uint16_t* __restrict__ wA1) {
    int j = blockIdx.x * 256 + threadIdx.x;
    if (j >= 1024) return;
    int oc = j >> 5, k = j & 31;
    wA1[j] = (k < 27) ? f2bf(W1[oc * 27 + k]) : (uint16_t)0;
}

// Wfc f32 -> bf16 (3,276,800 elems, 4 per thread)
__global__ __launch_bounds__(256) void k_prep_wfc(const float* __restrict__ Wfc,
                                                  uint16_t* __restrict__ wfcb) {
    int j = blockIdx.x * 256 + threadIdx.x;
    float4 v = ((const float4*)Wfc)[j];
    ushort4 o;
    o.x = f2bf(v.x);
    o.y = f2bf(v.y);
    o.z = f2bf(v.z);
    o.w = f2bf(v.w);
    ((ushort4*)wfcb)[j] = o;
}

// ---------------------------------------------------------------------------
// Kernel A: handcrafted features. One block per (channel, image).
// ---------------------------------------------------------------------------
__global__ __launch_bounds__(256) void k_handcrafted(const float* __restrict__ img,
                                                     float* __restrict__ f) {
    __shared__ float p[128 * 128];
    int c = blockIdx.x, b = blockIdx.y;
    const float* src = img + (((size_t)(b * 3 + c)) << 14);
    int tid = threadIdx.x;
    float sum = 0.f, sumsq = 0.f;
    for (int it = 0; it < 64; ++it) {
        int idx = tid + (it << 8);
        float v = floorf(src[idx] * 255.0f);
        p[idx] = v;
        sum += v;
        sumsq += v * v;
    }
    __syncthreads();
    float esum = 0.f;
    for (int it = 0; it < 64; ++it) {
        int idx = tid + (it << 8);
        int r = idx >> 7, cc = idx & 127;
        int rm = (r == 0) ? 1 : (r - 1), rp = (r == 127) ? 126 : (r + 1);
        int cm = (cc == 0) ? 1 : (cc - 1), cp = (cc == 127) ? 126 : (cc + 1);
        float a0 = p[(rm << 7) + cm], a1 = p[(rm << 7) + cc], a2 = p[(rm << 7) + cp];
        float b0 = p[(r << 7) + cm], b2 = p[(r << 7) + cp];
        float c0 = p[(rp << 7) + cm], c1 = p[(rp << 7) + cc], c2 = p[(rp << 7) + cp];
        float gx = (a2 - a0) + 2.f * (b2 - b0) + (c2 - c0);
        float gy = (c0 + 2.f * c1 + c2) - (a0 + 2.f * a1 + a2);
        esum += sqrtf(gx * gx + gy * gy);
    }
    for (int off = 32; off; off >>= 1) {
        sum += __shfl_down(sum, off);
        sumsq += __shfl_down(sumsq, off);
        esum += __shfl_down(esum, off);
    }
    __syncthreads();
    int w = tid >> 6;
    if ((tid & 63) == 0) {
        p[w * 3 + 0] = sum;
        p[w * 3 + 1] = sumsq;
        p[w * 3 + 2] = esum;
    }
    __syncthreads();
    if (tid == 0) {
        float S = 0.f, Q = 0.f, E = 0.f;
        for (int i = 0; i < 4; ++i) {
            S += p[i * 3 + 0];
            Q += p[i * 3 + 1];
            E += p[i * 3 + 2];
        }
        const float inv = 1.0f / 16384.0f;
        float mean = S * inv;
        float var = Q * inv - mean * mean;
        f[b * 16 + c] = E * inv;
        f[b * 16 + 3 + c] = mean;
        f[b * 16 + 6 + c] = sqrtf(fmaxf(var, 0.f));
    }
}

// ---------------------------------------------------------------------------
// Kernel B: conv1 via MFMA implicit GEMM. K=32 (27 taps zero-padded).
// ---------------------------------------------------------------------------
__global__ __launch_bounds__(256) void k_conv1_mfma(const float* __restrict__ img,
                                                    const uint16_t* __restrict__ wA1,
                                                    const float* __restrict__ b1,
                                                    uint16_t* __restrict__ pooled1) {
    __shared__ float s_in[3 * 34 * 34];      // 13872 B
    __shared__ uint16_t s_out[16 * 16 * 32]; // 16384 B: [py][px][oc]
    const int tile = blockIdx.x;
    const int b = blockIdx.y;
    const int ty = tile >> 2, tx = tile & 3;
    const int Y0 = ty * 32, X0 = tx * 32;
    const int tid = threadIdx.x;

    for (int j = tid; j < 3 * 1156; j += 256) {
        int ic = j / 1156;
        int rem = j - ic * 1156;
        int r = rem / 34, cc2 = rem - r * 34;
        int gy = Y0 - 1 + r, gx = X0 - 1 + cc2;
        float v = 0.f;
        if ((unsigned)gy < 128u && (unsigned)gx < 128u)
            v = img[(((size_t)b * 3 + ic) << 14) + (gy << 7) + gx];
        s_in[j] = v;
    }

    const int wv = tid >> 6, lane = tid & 63;
    const int rowl = lane & 15, kg = lane >> 4;

    int off[8];
#pragma unroll
    for (int i = 0; i < 8; ++i) {
        int k = kg * 8 + i;
        int ic = (k * 57) >> 9;
        int rem = k - 9 * ic;
        int dy = (rem * 11) >> 5;
        int dx = rem - 3 * dy;
        off[i] = (k < 27) ? (ic * 1156 + dy * 34 + dx) : 0;
    }

    bf16x8 afr[2];
#pragma unroll
    for (int g = 0; g < 2; ++g)
        afr[g] = *(const bf16x8*)(wA1 + (g * 16 + rowl) * 32 + kg * 8);
    float bias[2][4];
#pragma unroll
    for (int g = 0; g < 2; ++g)
#pragma unroll
        for (int r = 0; r < 4; ++r)
            bias[g][r] = b1[g * 16 + kg * 4 + r];

    __syncthreads();

    for (int rp = 0; rp < 4; ++rp) {
#pragma unroll
        for (int seg = 0; seg < 2; ++seg) {
            f32x4 acc[2][2];
#pragma unroll
            for (int rr = 0; rr < 2; ++rr)
#pragma unroll
                for (int g = 0; g < 2; ++g)
#pragma unroll
                    for (int r = 0; r < 4; ++r) acc[rr][g][r] = bias[g][r];

#pragma unroll
            for (int rr = 0; rr < 2; ++rr) {
                int ly = wv * 8 + rp * 2 + rr;
                int base = ly * 34 + seg * 16 + rowl;
                float v[8];
#pragma unroll
                for (int i = 0; i < 8; ++i) v[i] = s_in[base + off[i]];
                bf16x8 bf;
#pragma unroll
                for (int i = 0; i < 8; ++i) bf[i] = (__bf16)v[i];
#pragma unroll
                for (int g = 0; g < 2; ++g)
                    acc[rr][g] = __builtin_amdgcn_mfma_f32_16x16x32_bf16(afr[g], bf, acc[rr][g], 0, 0, 0);
            }
#pragma unroll
            for (int g = 0; g < 2; ++g)
#pragma unroll
                for (int r = 0; r < 4; ++r) {
                    float m = fmaxf(acc[0][g][r], acc[1][g][r]);
                    m = fmaxf(m, 0.f);
                    float o = fmaxf(m, __shfl_xor(m, 1));
                    if (!(lane & 1)) {
                        int py = wv * 4 + rp;
                        int px = seg * 8 + (rowl >> 1);
                        int oc = g * 16 + kg * 4 + r;
                        s_out[(py * 16 + px) * 32 + oc] = f2bf(o);
                    }
                }
        }
    }
    __syncthreads();
    {
        int py = tid >> 4, px = tid & 15;
        const uint4* src = (const uint4*)&s_out[tid * 32];
        uint4* dst = (uint4*)pooled1 +
                     ((((size_t)b << 12) + (ty * 16 + py) * 64 + tx * 16 + px) << 2);
#pragma unroll
        for (int q = 0; q < 4; ++q) dst[q] = src[q];
    }
}

// ---------------------------------------------------------------------------
// Kernel C: conv2 via MFMA implicit GEMM (tap-decomposed, K=32 per tap).
// ---------------------------------------------------------------------------
__global__ __launch_bounds__(256) void k_conv2_mfma(const uint16_t* __restrict__ pooled1,
                                                    const uint16_t* __restrict__ wA,
                                                    const float* __restrict__ b2v,
                                                    uint16_t* __restrict__ pooled2) {
    __shared__ uint16_t s_in[10 * 34 * 32];   // 21760 B
    __shared__ uint16_t s_out[64 * 4 * 16];   // 8192 B
    const int bx = blockIdx.x;
    const int b = blockIdx.y;
    const int tx = bx >> 3, ty = bx & 7;
    const int X0 = tx * 32, Y0 = ty * 8;
    const int tid = threadIdx.x;

    for (int j = tid; j < 1360; j += 256) {
        int r = j / 136;
        int rem = j - r * 136;
        int px = rem >> 2, c4 = rem & 3;
        int gy = Y0 - 1 + r, gx = X0 - 1 + px;
        uint4 v = make_uint4(0, 0, 0, 0);
        if ((unsigned)gy < 64u && (unsigned)gx < 64u)
            v = ((const uint4*)pooled1)[((((size_t)b << 12) + gy * 64 + gx) << 2) + c4];
        *(uint4*)&s_in[(r * 34 + px) * 32 + c4 * 8] = v;
    }

    const int wv = tid >> 6, lane = tid & 63;
    const int ocq = wv & 1, xth = wv >> 1;
    const int rowl = lane & 15, kg = lane >> 4;

    bf16x8 afr[9][2];
#pragma unroll
    for (int t = 0; t < 9; ++t)
#pragma unroll
        for (int g = 0; g < 2; ++g)
            afr[t][g] = *(const bf16x8*)(wA + t * 2048 + (ocq * 32 + g * 16 + rowl) * 32 + kg * 8);
    float bias[2][4];
#pragma unroll
    for (int g = 0; g < 2; ++g)
#pragma unroll
        for (int r = 0; r < 4; ++r)
            bias[g][r] = b2v[ocq * 32 + g * 16 + kg * 4 + r];

    __syncthreads();

    for (int yp = 0; yp < 4; ++yp) {
        f32x4 acc[2][2];
#pragma unroll
        for (int p = 0; p < 2; ++p)
#pragma unroll
            for (int g = 0; g < 2; ++g)
#pragma unroll
                for (int r = 0; r < 4; ++r) acc[p][g][r] = bias[g][r];

        bf16x8 bfr[4][3];
#pragma unroll
        for (int rr = 0; rr < 4; ++rr)
#pragma unroll
            for (int dx = 0; dx < 3; ++dx) {
                int pix = (2 * yp + rr) * 34 + xth * 16 + rowl + dx;
                bfr[rr][dx] = *(const bf16x8*)(s_in + pix * 32 + kg * 8);
            }
#pragma unroll
        for (int dy = 0; dy < 3; ++dy)
#pragma unroll
            for (int dx = 0; dx < 3; ++dx) {
                int t = dy * 3 + dx;
#pragma unroll
                for (int g = 0; g < 2; ++g) {
                    acc[0][g] = __builtin_amdgcn_mfma_f32_16x16x32_bf16(afr[t][g], bfr[dy][dx], acc[0][g], 0, 0, 0);
                    acc[1][g] = __builtin_amdgcn_mfma_f32_16x16x32_bf16(afr[t][g], bfr[dy + 1][dx], acc[1][g], 0, 0, 0);
                }
            }
#pragma unroll
        for (int g = 0; g < 2; ++g)
#pragma unroll
            for (int r = 0; r < 4; ++r) {
                float m = fmaxf(acc[0][g][r], acc[1][g][r]);
                m = fmaxf(m, 0.f);
                float o = fmaxf(m, __shfl_xor(m, 1));
                if (!(lane & 1)) {
                    int oc = ocq * 32 + g * 16 + kg * 4 + r;
                    int px = xth * 8 + (rowl >> 1);
                    s_out[(oc * 4 + yp) * 16 + px] = f2bf(o);
                }
            }
    }
    __syncthreads();
    const int PY0 = ty * 4, PX0 = tx * 16;
    for (int j = tid; j < 512; j += 256) {
        int oc = j >> 3, py = (j >> 1) & 3, h = j & 1;
        uint4 v = *(const uint4*)&s_out[(oc * 4 + py) * 16 + h * 8];
        *(uint4*)&pooled2[(((size_t)b * 64 + oc) << 10) + (PY0 + py) * 32 + PX0 + h * 8] = v;
    }
}

// ---------------------------------------------------------------------------
// Kernel D1a: attention conv partials. Grid (8 ch-chunks, B).
// pattn layout: [cc][b][1024] f32
// ---------------------------------------------------------------------------
__global__ __launch_bounds__(256) void k_attn_part(const uint16_t* __restrict__ pooled2,
                                                   const float* __restrict__ Wa,
                                                   float* __restrict__ pattn) {
    __shared__ uint16_t s_in[8 * 38 * 38];  // 23104 B
    int cc = blockIdx.x;
    int b = blockIdx.y;
    int tid = threadIdx.x;
    for (int j = tid; j < 8 * 1444; j += 256) {
        int ch = j / 1444;
        int rem = j - ch * 1444;
        int r = rem / 38, c2 = rem - r * 38;
        int gy = r - 3, gx = c2 - 3;
        uint16_t v = 0;
        if ((unsigned)gy < 32u && (unsigned)gx < 32u)
            v = pooled2[(((size_t)b * 64 + cc * 8 + ch) << 10) + (gy << 5) + gx];
        s_in[j] = v;
    }
    __syncthreads();

    int y0 = (tid >> 4) * 2, x0 = (tid & 15) * 2;
    float acc[4] = {0.f, 0.f, 0.f, 0.f};
    for (int ch = 0; ch < 8; ++ch) {
        float win[8][8];
#pragma unroll
        for (int r = 0; r < 8; ++r)
#pragma unroll
            for (int cp = 0; cp < 4; ++cp) {
                uint32_t v = *(const uint32_t*)&s_in[ch * 1444 + (y0 + r) * 38 + x0 + 2 * cp];
                win[r][2 * cp] = bf2f((uint16_t)(v & 0xffffu));
                win[r][2 * cp + 1] = bf2f((uint16_t)(v >> 16));
            }
        const float* w = Wa + (cc * 8 + ch) * 49;
#pragma unroll
        for (int a = 0; a < 2; ++a)
#pragma unroll
            for (int bb = 0; bb < 2; ++bb) {
                float s = 0.f;
#pragma unroll
                for (int dy = 0; dy < 7; ++dy)
#pragma unroll
                    for (int dx = 0; dx < 7; ++dx)
                        s += w[dy * 7 + dx] * win[a + dy][bb + dx];
                acc[a * 2 + bb] += s;
            }
    }
#pragma unroll
    for (int a = 0; a < 2; ++a)
#pragma unroll
        for (int bb = 0; bb < 2; ++bb)
            pattn[(((size_t)cc * 256 + b) << 10) + ((y0 + a) << 5) + (x0 + bb)] = acc[a * 2 + bb];
}

// Kernel D1b: reduce 8 partials + bias + sigmoid -> attn [B,1024] f32
__global__ __launch_bounds__(256) void k_attn_reduce(const float* __restrict__ pattn,
                                                     const float* __restrict__ ba,
                                                     float* __restrict__ attn) {
    int b = blockIdx.x;
    int tid = threadIdx.x;
    float a0 = ba[0];
    float4 s = make_float4(a0, a0, a0, a0);
#pragma unroll
    for (int cc = 0; cc < 8; ++cc) {
        float4 v = ((const float4*)&pattn[(((size_t)cc * 256 + b) << 10)])[tid];
        s.x += v.x;
        s.y += v.y;
        s.z += v.z;
        s.w += v.w;
    }
    float4 o;
    o.x = 1.f / (1.f + __expf(-s.x));
    o.y = 1.f / (1.f + __expf(-s.y));
    o.z = 1.f / (1.f + __expf(-s.z));
    o.w = 1.f / (1.f + __expf(-s.w));
    ((float4*)&attn[((size_t)b << 10)])[tid] = o;
}

// ---------------------------------------------------------------------------
// Kernel D2: FC via MFMA. C[oc=64][img=256] split-K over 64 chunks of 1024.
// Grid (16 img-tiles, 64 kc). Block = 256 thr = 4 waves; wave wv -> oc group
// wv*16..+15; each wave does 32 substeps of {global A-load, LDS B-read, MFMA}.
// xh LDS layout [k8][im] (16B units) -> conflict-free writes, near-floor reads.
// partial layout: [64 kc][256 img][64 oc] f32.
// ---------------------------------------------------------------------------
__global__ __launch_bounds__(256) void k_fc_mfma(const uint16_t* __restrict__ pooled2,
                                                 const float* __restrict__ attn,
                                                 const uint16_t* __restrict__ wfcb,
                                                 float* __restrict__ partial) {
    __shared__ uint16_t xh[128 * 128];  // 32 KB: elem idx = k8*128 + im*8
    const int it = blockIdx.x;   // 0..15
    const int kc = blockIdx.y;   // 0..63
    const int b0 = it * 16;
    const int K0 = kc * 1024;
    const int tid = threadIdx.x;

    // stage xhat = pooled2 * attn for 16 images x 1024 k (8 bf16 per thread-iter)
    for (int j = tid; j < 2048; j += 256) {
        int im = j >> 7, k8 = j & 127;
        int bimg = b0 + im;
        uint4 pv = *(const uint4*)&pooled2[((size_t)bimg << 16) + K0 + k8 * 8];
        const float* ap = &attn[((size_t)bimg << 10) + k8 * 8];
        float a[8];
        *(float4*)a = *(const float4*)ap;
        *(float4*)(a + 4) = *(const float4*)(ap + 4);
        uint16_t s[8];
        *(uint4*)s = pv;
        uint16_t d[8];
#pragma unroll
        for (int i = 0; i < 8; ++i) d[i] = f2bf(bf2f(s[i]) * a[i]);
        *(uint4*)&xh[k8 * 128 + im * 8] = *(uint4*)d;
    }

    const int wv = tid >> 6, lane = tid & 63;
    const int rowl = lane & 15, kg = lane >> 4;
    const uint16_t* wbase = wfcb + (size_t)(wv * 16 + rowl) * 65536 + K0 + kg * 8;

    __syncthreads();

    f32x4 acc = {0.f, 0.f, 0.f, 0.f};
#pragma unroll 4
    for (int kk = 0; kk < 32; ++kk) {
        bf16x8 af = *(const bf16x8*)(wbase + kk * 32);
        bf16x8 bf = *(const bf16x8*)&xh[(kk * 4 + kg) * 128 + rowl * 8];
        acc = __builtin_amdgcn_mfma_f32_16x16x32_bf16(af, bf, acc, 0, 0, 0);
    }
    // C/D: col = lane&15 = img-local, row = kg*4+r = oc-local
    float* pp = &partial[(((size_t)kc * 256 + (b0 + rowl)) << 6) + wv * 16 + kg * 4];
    *(f32x4*)pp = acc;
}

// ---------------------------------------------------------------------------
// Kernel E: MLP head + fusion. One wave per image.
// ---------------------------------------------------------------------------
__global__ __launch_bounds__(64) void k_head(const float* __restrict__ fbuf,
                                             const float* __restrict__ partial,
                                             const float* __restrict__ Wh1, const float* __restrict__ bh1,
                                             const float* __restrict__ Wh2, const float* __restrict__ bh2,
                                             const float* __restrict__ Wh3, const float* __restrict__ bh3,
                                             const float* __restrict__ bfc,
                                             const float* __restrict__ Wf, const float* __restrict__ bf_,
                                             const float* __restrict__ Wc, const float* __restrict__ bc,
                                             float* __restrict__ out) {
    __shared__ float fl[9];
    __shared__ float h1[32];
    __shared__ float h2[64];
    __shared__ float cat[100];
    int b = blockIdx.x;
    int l = threadIdx.x;
    if (l < 9) fl[l] = fbuf[b * 16 + l];
    __syncthreads();
    if (l < 32) {
        float a = bh1[l];
        for (int i = 0; i < 9; ++i) a += fl[i] * Wh1[l * 9 + i];
        h1[l] = fmaxf(a, 0.f);
    }
    __syncthreads();
    {
        float a = bh2[l];
        for (int i = 0; i < 32; ++i) a += h1[i] * Wh2[l * 32 + i];
        h2[l] = fmaxf(a, 0.f);
    }
    __syncthreads();
    if (l < 50) {
        float a = bh3[l];
        for (int i = 0; i < 64; ++i) a += h2[i] * Wh3[l * 64 + i];
        cat[50 + l] = fmaxf(a, 0.f);
        float s = bfc[l];
        for (int kc2 = 0; kc2 < 64; ++kc2) s += partial[(((size_t)kc2 * 256 + b) << 6) + l];
        cat[l] = fmaxf(s, 0.f);
    }
    __syncthreads();
    float a = bf_[l];
    for (int i = 0; i < 100; ++i) a += cat[i] * Wf[l * 100 + i];
    a = fmaxf(a, 0.f);
    float v = a * Wc[l];
    for (int off = 32; off; off >>= 1) v += __shfl_down(v, off);
    if (l == 0) out[b] = 1.f / (1.f + __expf(-(v + bc[0])));
}

// ---------------------------------------------------------------------------
extern "C" void kernel_launch(void* const* d_in, const int* in_sizes, int n_in,
                              void* d_out, int out_size, void* d_ws, size_t ws_size,
                              hipStream_t stream) {
    const float* images = (const float*)d_in[0];
    const float* W1 = (const float*)d_in[1];
    const float* b1 = (const float*)d_in[2];
    const float* W2 = (const float*)d_in[3];
    const float* b2 = (const float*)d_in[4];
    const float* Wa = (const float*)d_in[5];
    const float* ba = (const float*)d_in[6];
    const float* Wfc = (const float*)d_in[7];
    const float* bfc = (const float*)d_in[8];
    const float* Wh1 = (const float*)d_in[9];
    const float* bh1 = (const float*)d_in[10];
    const float* Wh2 = (const float*)d_in[11];
    const float* bh2 = (const float*)d_in[12];
    const float* Wh3 = (const float*)d_in[13];
    const float* bh3 = (const float*)d_in[14];
    const float* Wf = (const float*)d_in[15];
    const float* bf_ = (const float*)d_in[16];
    const float* Wc = (const float*)d_in[17];
    const float* bc = (const float*)d_in[18];

    // workspace layout (bytes)
    //   pooled1 bf16 NHWC [256,64,64,32] : 67108864   @ 0
    //     after conv2, this region is dead and re-used as:
    //       wfcb    bf16 [50,65536]      : 6553600    @ 0   (+garbage rows to 8.39MB, never read as oc>=50 unused)
    //       pattn   f32  [8,256,1024]    : 8388608    @ 8388608
    //       partial f32  [64,256,64]     : 4194304    @ 16777216
    //   pooled2 bf16 NCHW [256,64,32,32] : 33554432   @ 67108864
    //   attn    f32  [256,32,32]         : 1048576    @ 100663296
    //   fbuf    f32  [256,16]            : 16384      @ 101711872
    //   (old partial region @101728256 unused)
    //   wA      bf16 [9,64,32]           : 36864      @ 102776832
    //   wA1     bf16 [32,32]             : 2048       @ 102813696
    const size_t NEEDED = 102815744;
    if (ws_size < NEEDED) return;

    char* ws = (char*)d_ws;
    uint16_t* pooled1 = (uint16_t*)ws;
    uint16_t* pooled2 = (uint16_t*)(ws + 67108864);
    float* attn = (float*)(ws + 100663296);
    float* fbuf = (float*)(ws + 101711872);
    uint16_t* wA = (uint16_t*)(ws + 102776832);
    uint16_t* wA1 = (uint16_t*)(ws + 102813696);
    uint16_t* wfcb = (uint16_t*)ws;            // alias pooled1 (dead after conv2)
    float* pattn = (float*)(ws + 8388608);     // alias pooled1 (dead after conv2)
    float* partial = (float*)(ws + 16777216);  // alias pooled1 (dead after conv2)
    float* out = (float*)d_out;

    hipLaunchKernelGGL(k_prep_w2, dim3(72), dim3(256), 0, stream, W2, wA);
    hipLaunchKernelGGL(k_prep_w1, dim3(4), dim3(256), 0, stream, W1, wA1);
    hipLaunchKernelGGL(k_handcrafted, dim3(3, 256), dim3(256), 0, stream, images, fbuf);
    hipLaunchKernelGGL(k_conv1_mfma, dim3(16, 256), dim3(256), 0, stream, images, wA1, b1, pooled1);
    hipLaunchKernelGGL(k_conv2_mfma, dim3(16, 256), dim3(256), 0, stream, pooled1, wA, b2, pooled2);
    // pooled1 dead from here
    hipLaunchKernelGGL(k_prep_wfc, dim3(3200), dim3(256), 0, stream, Wfc, wfcb);
    hipLaunchKernelGGL(k_attn_part, dim3(8, 256), dim3(256), 0, stream, pooled2, Wa, pattn);
    hipLaunchKernelGGL(k_attn_reduce, dim3(256), dim3(256), 0, stream, pattn, ba, attn);
    hipLaunchKernelGGL(k_fc_mfma, dim3(16, 64), dim3(256), 0, stream, pooled2, attn, wfcb, partial);
    hipLaunchKernelGGL(k_head, dim3(256), dim3(64), 0, stream, fbuf, partial,
                       Wh1, bh1, Wh2, bh2, Wh3, bh3, bfc, Wf, bf_, Wc, bc, out);
}